// Round 13
// baseline (216.803 us; speedup 1.0000x reference)
//
#include <hip/hip_runtime.h>
#include <hip/hip_bf16.h>
#include <math.h>

// Problem constants
#define NRES 512
#define CS 384
#define CZ 128
#define NH 12
#define CC 16
#define NQP 4
#define NPV 8
#define HC (NH*CC)        // 192
#define FTOT 1152         // 192*3 + 144*2 + 288
#define CATF 2112         // 192 + 288 + 96 + 1536
#define FSPLIT 8
#define FCHUNK 264        // 2112/8
#define WO_I 16
#define NB_GEMM 64
#define W_C 0.23570226039551584f   // sqrt(2/(9*4))
#define W_L 0.5773502691896258f    // sqrt(1/3)

// ------- Kernel 1 (merged): gemm (blocks 0..63) || bias (blocks 64..4159) -------
// Gemm: 8 residues/block, all 1152 f via 3 strided f-passes; s-row operands
// wave-uniform -> s_load. Bias: R12 structure at 512 threads (8 partials).
__global__ __launch_bounds__(512) void k_gb(
    const float* __restrict__ s,
    const float* __restrict__ Wq, const float* __restrict__ bq,
    const float* __restrict__ Wk, const float* __restrict__ bk,
    const float* __restrict__ Wv, const float* __restrict__ bv,
    const float* __restrict__ Wqp, const float* __restrict__ bqp,
    const float* __restrict__ Wkp, const float* __restrict__ bkp,
    const float* __restrict__ Wvp, const float* __restrict__ bvp,
    float* __restrict__ p_raw,
    const float* __restrict__ z, const float* __restrict__ Wb,
    const float* __restrict__ bb, float* __restrict__ bias)
{
    int tid = threadIdx.x;
    __shared__ float zl[64*132];          // 33.8KB (bias path only)
    __shared__ float partial[8][12][64];  // 24KB
    __shared__ float bbl[12];

    if (blockIdx.x < NB_GEMM) {
        // ---------------- gemm path ----------------
        int r0 = blockIdx.x * 8;
        const float* srow = s + (size_t)r0 * CS;
        for (int fo = 0; fo < 3; ++fo) {
            int f = fo*512 + tid;
            if (f >= FTOT) break;
            const float* W; const float* bia; int col; int stride;
            if      (f < 192) { W = Wq;  bia = bq;  col = f;       stride = 192; }
            else if (f < 384) { W = Wk;  bia = bk;  col = f - 192; stride = 192; }
            else if (f < 576) { W = Wv;  bia = bv;  col = f - 384; stride = 192; }
            else if (f < 720) { W = Wqp; bia = bqp; col = f - 576; stride = 144; }
            else if (f < 864) { W = Wkp; bia = bkp; col = f - 720; stride = 144; }
            else              { W = Wvp; bia = bvp; col = f - 864; stride = 288; }
            float acc[8];
            float b0 = bia[col];
            #pragma unroll
            for (int j = 0; j < 8; ++j) acc[j] = b0;
            #pragma unroll 4
            for (int i = 0; i < CS; ++i) {
                float w = W[(size_t)i * stride + col];
                #pragma unroll
                for (int j = 0; j < 8; ++j) acc[j] = fmaf(w, srow[j*CS + i], acc[j]);
            }
            #pragma unroll
            for (int j = 0; j < 8; ++j) p_raw[(size_t)(r0 + j)*FTOT + f] = acc[j];
        }
        return;
    }

    // ---------------- bias path ----------------
    int bx = blockIdx.x - NB_GEMM;
    int i = bx >> 3, j0 = (bx & 7) * 64;
    int r = tid & 63, p = tid >> 6;       // p = wave index 0..7

    if (tid < 12) bbl[tid] = bb[tid];
    const float4* zsrc = reinterpret_cast<const float4*>(z + ((size_t)i*NRES + j0)*CZ);
    #pragma unroll
    for (int it = 0; it < 4; ++it) {
        int idx = it*512 + tid;
        int j = idx >> 5, c4 = idx & 31;
        *reinterpret_cast<float4*>(&zl[j*132 + c4*4]) = zsrc[idx];
    }
    __syncthreads();

    float acc[12] = {0,0,0,0,0,0,0,0,0,0,0,0};
    for (int it = 0; it < 4; ++it) {
        int c4 = __builtin_amdgcn_readfirstlane(p*4 + it);   // wave-uniform
        const float* wb = Wb + c4*48;    // rows c4*4..+3 of [128][12]
        float4 zv = *reinterpret_cast<const float4*>(&zl[r*132 + c4*4]);
        #pragma unroll
        for (int h = 0; h < 12; ++h) {
            acc[h] = fmaf(zv.x, wb[h],
                     fmaf(zv.y, wb[12+h],
                     fmaf(zv.z, wb[24+h],
                     fmaf(zv.w, wb[36+h], acc[h]))));
        }
    }
    #pragma unroll
    for (int h = 0; h < 12; ++h) partial[p][h][r] = acc[h];
    __syncthreads();

    for (int u = 0; u < 2; ++u) {
        int idx = u*512 + tid;
        if (idx < 768) {
            int h = idx >> 6, rr = idx & 63;
            float v = bbl[h];
            #pragma unroll
            for (int pp = 0; pp < 8; ++pp) v += partial[pp][h][rr];
            bias[((size_t)h*NRES + i)*NRES + j0 + rr] = v;
        }
    }
}

// ---------------- Kernel 1b: warp + transpose layouts ----------------
__global__ __launch_bounds__(256) void k_post(
    const float* __restrict__ p_raw, const float* __restrict__ T,
    float* __restrict__ q_s, float4* __restrict__ k_t4, float4* __restrict__ v_t4,
    float* __restrict__ wq, float4* __restrict__ wk_t4, float4* __restrict__ wv_t4,
    float* __restrict__ qn, float* __restrict__ kn)
{
    int n = blockIdx.x;
    int tid = threadIdx.x;
    __shared__ float pl[FTOT];
    __shared__ float Rl[9], tl[3];
    __shared__ float wq_l[144], wk_l[144], wv_l[288];
    __shared__ float sq_part[48], sk_part[48];

    for (int idx = tid; idx < FTOT/4; idx += 256)
        *reinterpret_cast<float4*>(&pl[idx*4]) =
            *reinterpret_cast<const float4*>(&p_raw[(size_t)n*FTOT + idx*4]);
    if (tid < 9)  Rl[tid] = T[n*16 + (tid/3)*4 + (tid%3)];
    if (tid >= 16 && tid < 19) tl[tid-16] = T[n*16 + (tid-16)*4 + 3];
    __syncthreads();

    if (tid < 48) {
        int h = tid >> 2, p = tid & 3;
        float qy0 = pl[576 + 0*48 + h*4 + p], qy1 = pl[576 + 1*48 + h*4 + p], qy2 = pl[576 + 2*48 + h*4 + p];
        float ky0 = pl[720 + 0*48 + h*4 + p], ky1 = pl[720 + 1*48 + h*4 + p], ky2 = pl[720 + 2*48 + h*4 + p];
        float qs2 = 0.f, ks2 = 0.f;
        #pragma unroll
        for (int x = 0; x < 3; ++x) {
            float wqv = Rl[x*3+0]*qy0 + Rl[x*3+1]*qy1 + Rl[x*3+2]*qy2 + tl[x];
            float wkv = Rl[x*3+0]*ky0 + Rl[x*3+1]*ky1 + Rl[x*3+2]*ky2 + tl[x];
            wq_l[h*12 + p*3 + x] = wqv;
            wk_l[h*12 + p*3 + x] = wkv;
            qs2 += wqv*wqv; ks2 += wkv*wkv;
        }
        sq_part[tid] = qs2; sk_part[tid] = ks2;
    } else if (tid >= 64 && tid < 160) {
        int u = tid - 64; int h = u >> 3, p = u & 7;
        float y0 = pl[864 + 0*96 + h*8 + p], y1 = pl[864 + 1*96 + h*8 + p], y2 = pl[864 + 2*96 + h*8 + p];
        #pragma unroll
        for (int x = 0; x < 3; ++x) {
            wv_l[h*24 + p*3 + x] = Rl[x*3+0]*y0 + Rl[x*3+1]*y1 + Rl[x*3+2]*y2 + tl[x];
        }
    }
    __syncthreads();

    if (tid < 48) {
        int h = tid >> 2, c4 = tid & 3;
        float4 qv = *reinterpret_cast<const float4*>(&pl[h*16 + c4*4]);
        qv.x *= 0.25f; qv.y *= 0.25f; qv.z *= 0.25f; qv.w *= 0.25f;
        float4 kv = *reinterpret_cast<const float4*>(&pl[192 + h*16 + c4*4]);
        float4 vv = *reinterpret_cast<const float4*>(&pl[384 + h*16 + c4*4]);
        *reinterpret_cast<float4*>(&q_s[((size_t)h*NRES + n)*16 + c4*4]) = qv;
        k_t4[((size_t)h*4 + c4)*NRES + n] = kv;
        v_t4[((size_t)h*4 + c4)*NRES + n] = vv;
    } else if (tid >= 64 && tid < 100) {
        int u = tid - 64; int h = u / 3, e4 = u % 3;
        float4 kv = *reinterpret_cast<const float4*>(&wk_l[h*12 + e4*4]);
        wk_t4[((size_t)h*3 + e4)*NRES + n] = kv;
    } else if (tid >= 104 && tid < 140) {
        int u = tid - 104; int h = u / 3, e4 = u % 3;
        float4 qv = *reinterpret_cast<const float4*>(&wq_l[h*12 + e4*4]);
        *reinterpret_cast<float4*>(&wq[((size_t)h*NRES + n)*12 + e4*4]) = qv;
    } else if (tid >= 160 && tid < 232) {
        int u = tid - 160; int h = u / 6, e4 = u % 6;
        float4 vv = *reinterpret_cast<const float4*>(&wv_l[h*24 + e4*4]);
        wv_t4[((size_t)h*6 + e4)*NRES + n] = vv;
    } else if (tid >= 232 && tid < 244) {
        int h = tid - 232;
        qn[(size_t)h*NRES + n] = sq_part[h*4] + sq_part[h*4+1] + sq_part[h*4+2] + sq_part[h*4+3];
        kn[(size_t)h*NRES + n] = sk_part[h*4] + sk_part[h*4+1] + sk_part[h*4+2] + sk_part[h*4+3];
    }
}

// ------- Kernel 3: att softmax for 2 residues/block (k/v rows loaded once) -------
__global__ __launch_bounds__(256) void k_att(
    const float* __restrict__ q_s, const float4* __restrict__ k_t4,
    const float* __restrict__ wq, const float4* __restrict__ wk_t4,
    const float* __restrict__ qn, const float* __restrict__ kn,
    const float* __restrict__ hw, const float* __restrict__ T,
    float* __restrict__ bias,       // in: bias, out: att
    const float4* __restrict__ v_t4, const float4* __restrict__ wv_t4,
    float* __restrict__ cat)
{
    int i0 = blockIdx.x * 2, h = blockIdx.y;
    int tid = threadIdx.x;
    int wave = tid >> 6, lane = tid & 63;
    __shared__ float ql[2][16], wql[2][12];
    __shared__ float att[2][NRES];
    __shared__ float redm[2][4], reds[2][4];
    __shared__ float optl[2][24];
    __shared__ float sQn[2], sG;

    if (tid < 32) {
        int ii = tid >> 4, c = tid & 15;
        ql[ii][c] = q_s[((size_t)h*NRES + i0+ii)*16 + c];
    } else if (tid < 56) {
        int u = tid - 32; int ii = u / 12, e = u % 12;
        wql[ii][e] = wq[((size_t)h*NRES + i0+ii)*12 + e];
    } else if (tid < 58) {
        int ii = tid - 56;
        sQn[ii] = qn[(size_t)h*NRES + i0+ii];
    } else if (tid == 58) {
        float x = hw[h];
        float sp = (x > 20.f) ? x : log1pf(expf(x));
        sG = sp * W_C * 0.5f;
    }
    __syncthreads();
    float gam = sG;

    float lg[2][2];
    #pragma unroll
    for (int m = 0; m < 2; ++m) {
        int j = tid + m*256;
        float4 kv0 = k_t4[((size_t)h*4 + 0)*NRES + j];
        float4 kv1 = k_t4[((size_t)h*4 + 1)*NRES + j];
        float4 kv2 = k_t4[((size_t)h*4 + 2)*NRES + j];
        float4 kv3 = k_t4[((size_t)h*4 + 3)*NRES + j];
        float4 wv0 = wk_t4[((size_t)h*3 + 0)*NRES + j];
        float4 wv1 = wk_t4[((size_t)h*3 + 1)*NRES + j];
        float4 wv2 = wk_t4[((size_t)h*3 + 2)*NRES + j];
        float knj = kn[(size_t)h*NRES + j];
        #pragma unroll
        for (int ii = 0; ii < 2; ++ii) {
            float qk = ql[ii][0]*kv0.x + ql[ii][1]*kv0.y + ql[ii][2]*kv0.z + ql[ii][3]*kv0.w
                     + ql[ii][4]*kv1.x + ql[ii][5]*kv1.y + ql[ii][6]*kv1.z + ql[ii][7]*kv1.w
                     + ql[ii][8]*kv2.x + ql[ii][9]*kv2.y + ql[ii][10]*kv2.z + ql[ii][11]*kv2.w
                     + ql[ii][12]*kv3.x + ql[ii][13]*kv3.y + ql[ii][14]*kv3.z + ql[ii][15]*kv3.w;
            float dd = wql[ii][0]*wv0.x + wql[ii][1]*wv0.y + wql[ii][2]*wv0.z + wql[ii][3]*wv0.w
                     + wql[ii][4]*wv1.x + wql[ii][5]*wv1.y + wql[ii][6]*wv1.z + wql[ii][7]*wv1.w
                     + wql[ii][8]*wv2.x + wql[ii][9]*wv2.y + wql[ii][10]*wv2.z + wql[ii][11]*wv2.w;
            float d2 = sQn[ii] + knj - 2.f*dd;
            lg[ii][m] = W_L * (qk + bias[((size_t)h*NRES + i0+ii)*NRES + j] - gam*d2);
        }
    }

    #pragma unroll
    for (int ii = 0; ii < 2; ++ii) {
        float mx = fmaxf(lg[ii][0], lg[ii][1]);
        #pragma unroll
        for (int d = 32; d > 0; d >>= 1) mx = fmaxf(mx, __shfl_xor(mx, d));
        if (lane == 0) redm[ii][wave] = mx;
    }
    __syncthreads();
    #pragma unroll
    for (int ii = 0; ii < 2; ++ii) {
        float mx = fmaxf(fmaxf(redm[ii][0], redm[ii][1]), fmaxf(redm[ii][2], redm[ii][3]));
        float e0 = __expf(lg[ii][0]-mx), e1 = __expf(lg[ii][1]-mx);
        lg[ii][0] = e0; lg[ii][1] = e1;
        float sm = e0 + e1;
        #pragma unroll
        for (int d = 32; d > 0; d >>= 1) sm += __shfl_xor(sm, d);
        if (lane == 0) reds[ii][wave] = sm;
    }
    __syncthreads();
    #pragma unroll
    for (int ii = 0; ii < 2; ++ii) {
        float inv = 1.f / (reds[ii][0]+reds[ii][1]+reds[ii][2]+reds[ii][3]);
        float a0 = lg[ii][0]*inv, a1 = lg[ii][1]*inv;
        att[ii][tid] = a0; att[ii][tid+256] = a1;
        bias[((size_t)h*NRES + i0+ii)*NRES + tid]       = a0;
        bias[((size_t)h*NRES + i0+ii)*NRES + tid + 256] = a1;
    }
    __syncthreads();

    for (int g = wave; g < 10; g += 4) {
        const float4* row = (g < 4) ? &v_t4[((size_t)h*4 + g)*NRES]
                                    : &wv_t4[((size_t)h*6 + (g-4))*NRES];
        float p0x=0,p0y=0,p0z=0,p0w=0, p1x=0,p1y=0,p1z=0,p1w=0;
        #pragma unroll
        for (int u = 0; u < 8; ++u) {
            int jr = lane + u*64;
            float4 r = row[jr];
            float a0 = att[0][jr], a1 = att[1][jr];
            p0x += a0*r.x; p0y += a0*r.y; p0z += a0*r.z; p0w += a0*r.w;
            p1x += a1*r.x; p1y += a1*r.y; p1z += a1*r.z; p1w += a1*r.w;
        }
        #pragma unroll
        for (int d = 32; d > 0; d >>= 1) {
            p0x += __shfl_down(p0x, d); p0y += __shfl_down(p0y, d);
            p0z += __shfl_down(p0z, d); p0w += __shfl_down(p0w, d);
            p1x += __shfl_down(p1x, d); p1y += __shfl_down(p1y, d);
            p1z += __shfl_down(p1z, d); p1w += __shfl_down(p1w, d);
        }
        if (lane == 0) {
            if (g < 4) {
                *reinterpret_cast<float4*>(&cat[(size_t)(i0+0)*CATF + h*16 + g*4]) =
                    make_float4(p0x, p0y, p0z, p0w);
                *reinterpret_cast<float4*>(&cat[(size_t)(i0+1)*CATF + h*16 + g*4]) =
                    make_float4(p1x, p1y, p1z, p1w);
            } else {
                int e = (g-4)*4;
                optl[0][e] = p0x; optl[0][e+1] = p0y; optl[0][e+2] = p0z; optl[0][e+3] = p0w;
                optl[1][e] = p1x; optl[1][e+1] = p1y; optl[1][e+2] = p1z; optl[1][e+3] = p1w;
            }
        }
    }
    __syncthreads();

    if (tid < 16) {
        int ii = tid >> 3, p = tid & 7;
        int i = i0 + ii;
        float t0 = T[i*16 + 0*4 + 3], t1 = T[i*16 + 1*4 + 3], t2 = T[i*16 + 2*4 + 3];
        float y0 = optl[ii][p*3+0] - t0, y1 = optl[ii][p*3+1] - t1, y2 = optl[ii][p*3+2] - t2;
        float n2 = 0.f;
        #pragma unroll
        for (int x = 0; x < 3; ++x) {
            float w = T[i*16 + 0*4 + x]*y0 + T[i*16 + 1*4 + x]*y1 + T[i*16 + 2*4 + x]*y2;
            cat[(size_t)i*CATF + 192 + x*96 + h*8 + p] = w;
            n2 += w*w;
        }
        cat[(size_t)i*CATF + 480 + h*8 + p] = sqrtf(n2);
    }
}

// ---------------- Kernel 4: pairwise = att @ z -> cat[576:2112] ----------------
__global__ __launch_bounds__(512) void k_pair(
    const float* __restrict__ z, const float* __restrict__ att,
    float* __restrict__ cat)
{
    int i = blockIdx.x, tid = threadIdx.x;
    int us = tid >> 7, ht = (tid >> 5) & 3, c4 = tid & 31;
    __shared__ float al[12*NRES];     // att, then reused as partial buffer

    for (int idx = tid; idx < 12*NRES; idx += 512) {
        int h = idx >> 9, j = idx & 511;
        al[idx] = att[((size_t)h*NRES + i)*NRES + j];
    }
    __syncthreads();

    const float4* z4 = reinterpret_cast<const float4*>(z + (size_t)i*NRES*CZ);
    float4 a0 = {0,0,0,0}, a1 = {0,0,0,0}, a2 = {0,0,0,0};
    int ub = us*128;
    #pragma unroll 4
    for (int u = 0; u < 128; ++u) {
        int jr = ub + u;
        float4 zv = z4[(size_t)jr*32 + c4];
        float w0 = al[(ht    )*NRES + jr];
        float w1 = al[(ht + 4)*NRES + jr];
        float w2 = al[(ht + 8)*NRES + jr];
        a0.x = fmaf(w0, zv.x, a0.x); a0.y = fmaf(w0, zv.y, a0.y);
        a0.z = fmaf(w0, zv.z, a0.z); a0.w = fmaf(w0, zv.w, a0.w);
        a1.x = fmaf(w1, zv.x, a1.x); a1.y = fmaf(w1, zv.y, a1.y);
        a1.z = fmaf(w1, zv.z, a1.z); a1.w = fmaf(w1, zv.w, a1.w);
        a2.x = fmaf(w2, zv.x, a2.x); a2.y = fmaf(w2, zv.y, a2.y);
        a2.z = fmaf(w2, zv.z, a2.z); a2.w = fmaf(w2, zv.w, a2.w);
    }
    __syncthreads();   // al reads done; reuse as partial buffer
    float* pr = al;    // [512 threads][12]
    {
        float* p = &pr[tid*12];
        p[0]=a0.x; p[1]=a0.y; p[2]=a0.z;  p[3]=a0.w;
        p[4]=a1.x; p[5]=a1.y; p[6]=a1.z;  p[7]=a1.w;
        p[8]=a2.x; p[9]=a2.y; p[10]=a2.z; p[11]=a2.w;
    }
    __syncthreads();

    for (int idx = tid; idx < 1536; idx += 512) {
        int h = idx >> 7, c = idx & 127;
        int hh = h & 3, m = h >> 2, cc4 = c >> 2, x = c & 3;
        float v = 0.f;
        #pragma unroll
        for (int uu = 0; uu < 4; ++uu)
            v += pr[(((uu*4 + hh)*32 + cc4))*12 + m*4 + x];
        cat[(size_t)i*CATF + 576 + h*128 + c] = v;
    }
}

// ---------------- Kernel 5a: split-K Wo GEMM (scalar cat operands, no LDS) ----------------
__global__ __launch_bounds__(384) void k_wo(
    const float* __restrict__ cat, const float* __restrict__ Wo,
    float* __restrict__ part)
{
    int i0 = blockIdx.x * WO_I;
    int fs = blockIdx.y;
    int f0 = fs * FCHUNK;
    int tid = threadIdx.x;
    const float* crow = cat + (size_t)i0*CATF + f0;
    float acc[WO_I];
    #pragma unroll
    for (int j = 0; j < WO_I; ++j) acc[j] = 0.f;
    const float* wp = Wo + (size_t)f0*CS + tid;
    #pragma unroll 4
    for (int f = 0; f < FCHUNK; ++f) {
        float w = wp[(size_t)f*CS];
        #pragma unroll
        for (int j = 0; j < WO_I; ++j)
            acc[j] = fmaf(w, crow[(size_t)j*CATF + f], acc[j]);
    }
    #pragma unroll
    for (int j = 0; j < WO_I; ++j)
        part[((size_t)fs*NRES + i0 + j)*CS + tid] = acc[j];
}

// ---------------- Kernel 5b: reduce partials + bias ----------------
__global__ __launch_bounds__(384) void k_red(
    const float* __restrict__ part, const float* __restrict__ bo,
    float* __restrict__ out)
{
    int i = blockIdx.x, o = threadIdx.x;
    float a = bo[o];
    #pragma unroll
    for (int s = 0; s < FSPLIT; ++s)
        a += part[((size_t)s*NRES + i)*CS + o];
    out[(size_t)i*CS + o] = a;
}

// ---------------- launch ----------------
extern "C" void kernel_launch(void* const* d_in, const int* in_sizes, int n_in,
                              void* d_out, int out_size, void* d_ws, size_t ws_size,
                              hipStream_t stream)
{
    const float* s   = (const float*)d_in[0];
    const float* z   = (const float*)d_in[1];
    const float* T   = (const float*)d_in[2];
    const float* Wq  = (const float*)d_in[3];  const float* bq  = (const float*)d_in[4];
    const float* Wk  = (const float*)d_in[5];  const float* bk  = (const float*)d_in[6];
    const float* Wv  = (const float*)d_in[7];  const float* bv  = (const float*)d_in[8];
    const float* Wqp = (const float*)d_in[9];  const float* bqp = (const float*)d_in[10];
    const float* Wkp = (const float*)d_in[11]; const float* bkp = (const float*)d_in[12];
    const float* Wvp = (const float*)d_in[13]; const float* bvp = (const float*)d_in[14];
    const float* Wb  = (const float*)d_in[15]; const float* bb  = (const float*)d_in[16];
    const float* Wo  = (const float*)d_in[17]; const float* bo  = (const float*)d_in[18];
    const float* hw  = (const float*)d_in[19];
    float* out = (float*)d_out;
    float* ws  = (float*)d_ws;

    size_t off = 0;
    float* q_s  = ws + off; off += (size_t)NH*NRES*CC;
    float* k_t  = ws + off; off += (size_t)NH*NRES*CC;
    float* v_t  = ws + off; off += (size_t)NH*NRES*CC;
    float* wq   = ws + off; off += (size_t)NH*NRES*12;
    float* wk_t = ws + off; off += (size_t)NH*NRES*12;
    float* wv_t = ws + off; off += (size_t)NH*NRES*24;
    float* qn   = ws + off; off += (size_t)NH*NRES;
    float* kn   = ws + off; off += (size_t)NH*NRES;
    float* bias = ws + off; off += (size_t)NH*NRES*NRES;
    float* cat  = ws + off; off += (size_t)NRES*CATF;
    float* part = ws + off; off += (size_t)FSPLIT*NRES*CS;
    float* praw = ws + off; off += (size_t)NRES*FTOT;

    // merged: gemm (64 blocks, first) || bias (4096 blocks)
    k_gb<<<dim3(NB_GEMM + 8*NRES), dim3(512), 0, stream>>>(
        s, Wq, bq, Wk, bk, Wv, bv, Wqp, bqp, Wkp, bkp, Wvp, bvp, praw,
        z, Wb, bb, bias);

    k_post<<<dim3(NRES), dim3(256), 0, stream>>>(
        praw, T, q_s, (float4*)k_t, (float4*)v_t, wq, (float4*)wk_t, (float4*)wv_t, qn, kn);

    k_att<<<dim3(NRES/2, NH), dim3(256), 0, stream>>>(
        q_s, (const float4*)k_t, wq, (const float4*)wk_t, qn, kn, hw, T, bias,
        (const float4*)v_t, (const float4*)wv_t, cat);

    k_pair<<<dim3(NRES), dim3(512), 0, stream>>>(z, bias, cat);

    k_wo<<<dim3(NRES/WO_I, FSPLIT), dim3(384), 0, stream>>>(cat, Wo, part);

    k_red<<<dim3(NRES), dim3(384), 0, stream>>>(part, bo, out);
}

// Round 14
// 177.888 us; speedup vs baseline: 1.2188x; 1.2188x over previous
//
#include <hip/hip_runtime.h>
#include <hip/hip_bf16.h>
#include <math.h>

// Problem constants
#define NRES 512
#define CS 384
#define CZ 128
#define NH 12
#define CC 16
#define NQP 4
#define NPV 8
#define HC (NH*CC)        // 192
#define FTOT 1152         // 192*3 + 144*2 + 288
#define CATF 2112         // 192 + 288 + 96 + 1536
#define FSPLIT 8
#define FCHUNK 264        // 2112/8
#define WO_I 16
#define W_C 0.23570226039551584f   // sqrt(2/(9*4))
#define W_L 0.5773502691896258f    // sqrt(1/3)

// ---------------- Kernel 1a: all projections as one GEMM ----------------
// grid (128, 3): 4 residues/block.
__global__ __launch_bounds__(384) void k_gemm(
    const float* __restrict__ s,
    const float* __restrict__ Wq, const float* __restrict__ bq,
    const float* __restrict__ Wk, const float* __restrict__ bk,
    const float* __restrict__ Wv, const float* __restrict__ bv,
    const float* __restrict__ Wqp, const float* __restrict__ bqp,
    const float* __restrict__ Wkp, const float* __restrict__ bkp,
    const float* __restrict__ Wvp, const float* __restrict__ bvp,
    float* __restrict__ p_raw)
{
    int r0 = blockIdx.x * 4;
    int f  = blockIdx.y * 384 + threadIdx.x;
    const float* W; const float* bia; int col; int stride;
    if      (f < 192) { W = Wq;  bia = bq;  col = f;       stride = 192; }
    else if (f < 384) { W = Wk;  bia = bk;  col = f - 192; stride = 192; }
    else if (f < 576) { W = Wv;  bia = bv;  col = f - 384; stride = 192; }
    else if (f < 720) { W = Wqp; bia = bqp; col = f - 576; stride = 144; }
    else if (f < 864) { W = Wkp; bia = bkp; col = f - 720; stride = 144; }
    else              { W = Wvp; bia = bvp; col = f - 864; stride = 288; }

    float acc[4];
    float b0 = bia[col];
    #pragma unroll
    for (int j = 0; j < 4; ++j) acc[j] = b0;

    const float* srow = s + (size_t)r0 * CS;
    #pragma unroll 4
    for (int i = 0; i < CS; ++i) {
        float w = W[(size_t)i * stride + col];
        #pragma unroll
        for (int j = 0; j < 4; ++j) acc[j] = fmaf(w, srow[j*CS + i], acc[j]);
    }
    #pragma unroll
    for (int j = 0; j < 4; ++j) p_raw[(size_t)(r0 + j)*FTOT + f] = acc[j];
}

// ---------------- Kernel 1b: warp + transpose layouts ----------------
__global__ __launch_bounds__(256) void k_post(
    const float* __restrict__ p_raw, const float* __restrict__ T,
    float* __restrict__ q_s, float4* __restrict__ k_t4, float4* __restrict__ v_t4,
    float* __restrict__ wq, float4* __restrict__ wk_t4, float4* __restrict__ wv_t4,
    float* __restrict__ qn, float* __restrict__ kn)
{
    int n = blockIdx.x;
    int tid = threadIdx.x;
    __shared__ float pl[FTOT];
    __shared__ float Rl[9], tl[3];
    __shared__ float wq_l[144], wk_l[144], wv_l[288];
    __shared__ float sq_part[48], sk_part[48];

    for (int idx = tid; idx < FTOT/4; idx += 256)
        *reinterpret_cast<float4*>(&pl[idx*4]) =
            *reinterpret_cast<const float4*>(&p_raw[(size_t)n*FTOT + idx*4]);
    if (tid < 9)  Rl[tid] = T[n*16 + (tid/3)*4 + (tid%3)];
    if (tid >= 16 && tid < 19) tl[tid-16] = T[n*16 + (tid-16)*4 + 3];
    __syncthreads();

    if (tid < 48) {
        int h = tid >> 2, p = tid & 3;
        float qy0 = pl[576 + 0*48 + h*4 + p], qy1 = pl[576 + 1*48 + h*4 + p], qy2 = pl[576 + 2*48 + h*4 + p];
        float ky0 = pl[720 + 0*48 + h*4 + p], ky1 = pl[720 + 1*48 + h*4 + p], ky2 = pl[720 + 2*48 + h*4 + p];
        float qs2 = 0.f, ks2 = 0.f;
        #pragma unroll
        for (int x = 0; x < 3; ++x) {
            float wqv = Rl[x*3+0]*qy0 + Rl[x*3+1]*qy1 + Rl[x*3+2]*qy2 + tl[x];
            float wkv = Rl[x*3+0]*ky0 + Rl[x*3+1]*ky1 + Rl[x*3+2]*ky2 + tl[x];
            wq_l[h*12 + p*3 + x] = wqv;
            wk_l[h*12 + p*3 + x] = wkv;
            qs2 += wqv*wqv; ks2 += wkv*wkv;
        }
        sq_part[tid] = qs2; sk_part[tid] = ks2;
    } else if (tid >= 64 && tid < 160) {
        int u = tid - 64; int h = u >> 3, p = u & 7;
        float y0 = pl[864 + 0*96 + h*8 + p], y1 = pl[864 + 1*96 + h*8 + p], y2 = pl[864 + 2*96 + h*8 + p];
        #pragma unroll
        for (int x = 0; x < 3; ++x) {
            wv_l[h*24 + p*3 + x] = Rl[x*3+0]*y0 + Rl[x*3+1]*y1 + Rl[x*3+2]*y2 + tl[x];
        }
    }
    __syncthreads();

    if (tid < 48) {
        int h = tid >> 2, c4 = tid & 3;
        float4 qv = *reinterpret_cast<const float4*>(&pl[h*16 + c4*4]);
        qv.x *= 0.25f; qv.y *= 0.25f; qv.z *= 0.25f; qv.w *= 0.25f;
        float4 kv = *reinterpret_cast<const float4*>(&pl[192 + h*16 + c4*4]);
        float4 vv = *reinterpret_cast<const float4*>(&pl[384 + h*16 + c4*4]);
        *reinterpret_cast<float4*>(&q_s[((size_t)h*NRES + n)*16 + c4*4]) = qv;
        k_t4[((size_t)h*4 + c4)*NRES + n] = kv;
        v_t4[((size_t)h*4 + c4)*NRES + n] = vv;
    } else if (tid >= 64 && tid < 100) {
        int u = tid - 64; int h = u / 3, e4 = u % 3;
        float4 kv = *reinterpret_cast<const float4*>(&wk_l[h*12 + e4*4]);
        wk_t4[((size_t)h*3 + e4)*NRES + n] = kv;
    } else if (tid >= 104 && tid < 140) {
        int u = tid - 104; int h = u / 3, e4 = u % 3;
        float4 qv = *reinterpret_cast<const float4*>(&wq_l[h*12 + e4*4]);
        *reinterpret_cast<float4*>(&wq[((size_t)h*NRES + n)*12 + e4*4]) = qv;
    } else if (tid >= 160 && tid < 232) {
        int u = tid - 160; int h = u / 6, e4 = u % 6;
        float4 vv = *reinterpret_cast<const float4*>(&wv_l[h*24 + e4*4]);
        wv_t4[((size_t)h*6 + e4)*NRES + n] = vv;
    } else if (tid >= 232 && tid < 244) {
        int h = tid - 232;
        qn[(size_t)h*NRES + n] = sq_part[h*4] + sq_part[h*4+1] + sq_part[h*4+2] + sq_part[h*4+3];
        kn[(size_t)h*NRES + n] = sk_part[h*4] + sk_part[h*4+1] + sk_part[h*4+2] + sk_part[h*4+3];
    }
}

// ---------------- Kernel 2: bias = z @ Wb + bb  -> [H][N][N] ----------------
// (R12 version: coalesced z->LDS once; Wb via scalar s_load path)
__global__ __launch_bounds__(256) void k_bias(
    const float* __restrict__ z, const float* __restrict__ Wb,
    const float* __restrict__ bb, float* __restrict__ bias)
{
    int j0 = blockIdx.x * 64, i = blockIdx.y;
    int tid = threadIdx.x;
    int r = tid & 63, p = tid >> 6;   // p = wave index (0..3)
    __shared__ float zl[64*132];
    __shared__ float partial[4][12][64];
    __shared__ float bbl[12];

    if (tid < 12) bbl[tid] = bb[tid];
    const float4* zsrc = reinterpret_cast<const float4*>(z + ((size_t)i*NRES + j0)*CZ);
    #pragma unroll
    for (int it = 0; it < 8; ++it) {
        int idx = it*256 + tid;
        int j = idx >> 5, c4 = idx & 31;
        *reinterpret_cast<float4*>(&zl[j*132 + c4*4]) = zsrc[idx];
    }
    __syncthreads();

    float acc[12] = {0,0,0,0,0,0,0,0,0,0,0,0};
    for (int it = 0; it < 8; ++it) {
        int c4 = __builtin_amdgcn_readfirstlane(p*8 + it);   // wave-uniform
        const float* wb = Wb + c4*48;
        float4 zv = *reinterpret_cast<const float4*>(&zl[r*132 + c4*4]);
        #pragma unroll
        for (int h = 0; h < 12; ++h) {
            acc[h] = fmaf(zv.x, wb[h],
                     fmaf(zv.y, wb[12+h],
                     fmaf(zv.z, wb[24+h],
                     fmaf(zv.w, wb[36+h], acc[h]))));
        }
    }
    #pragma unroll
    for (int h = 0; h < 12; ++h) partial[p][h][r] = acc[h];
    __syncthreads();

    #pragma unroll
    for (int u = 0; u < 3; ++u) {
        int idx = u*256 + tid;
        int h = idx >> 6, rr = idx & 63;
        float v = partial[0][h][rr] + partial[1][h][rr]
                + partial[2][h][rr] + partial[3][h][rr] + bbl[h];
        bias[((size_t)h*NRES + i)*NRES + j0 + rr] = v;
    }
}

// ------- Kernel 3: att softmax for 4 residues/block (k/v rows loaded once) -------
__global__ __launch_bounds__(256) void k_att(
    const float* __restrict__ q_s, const float4* __restrict__ k_t4,
    const float* __restrict__ wq, const float4* __restrict__ wk_t4,
    const float* __restrict__ qn, const float* __restrict__ kn,
    const float* __restrict__ hw, const float* __restrict__ T,
    float* __restrict__ bias,       // in: bias, out: att
    const float4* __restrict__ v_t4, const float4* __restrict__ wv_t4,
    float* __restrict__ cat)
{
    int i0 = blockIdx.x * 4, h = blockIdx.y;
    int tid = threadIdx.x;
    int wave = tid >> 6, lane = tid & 63;
    __shared__ float ql[4][16], wql[4][12];
    __shared__ float att[4][NRES];
    __shared__ float redm[4][4], reds[4][4];
    __shared__ float optl[4][24];
    __shared__ float sQn[4], sG;

    if (tid < 64) {
        int ii = tid >> 4, c = tid & 15;
        ql[ii][c] = q_s[((size_t)h*NRES + i0+ii)*16 + c];
    } else if (tid < 112) {
        int u = tid - 64; int ii = u / 12, e = u % 12;
        wql[ii][e] = wq[((size_t)h*NRES + i0+ii)*12 + e];
    } else if (tid < 116) {
        int ii = tid - 112;
        sQn[ii] = qn[(size_t)h*NRES + i0+ii];
    } else if (tid == 116) {
        float x = hw[h];
        float sp = (x > 20.f) ? x : log1pf(expf(x));
        sG = sp * W_C * 0.5f;
    }
    __syncthreads();
    float gam = sG;

    float lg[4][2];
    #pragma unroll
    for (int m = 0; m < 2; ++m) {
        int j = tid + m*256;
        float4 kv0 = k_t4[((size_t)h*4 + 0)*NRES + j];
        float4 kv1 = k_t4[((size_t)h*4 + 1)*NRES + j];
        float4 kv2 = k_t4[((size_t)h*4 + 2)*NRES + j];
        float4 kv3 = k_t4[((size_t)h*4 + 3)*NRES + j];
        float4 wv0 = wk_t4[((size_t)h*3 + 0)*NRES + j];
        float4 wv1 = wk_t4[((size_t)h*3 + 1)*NRES + j];
        float4 wv2 = wk_t4[((size_t)h*3 + 2)*NRES + j];
        float knj = kn[(size_t)h*NRES + j];
        #pragma unroll
        for (int ii = 0; ii < 4; ++ii) {
            float qk = ql[ii][0]*kv0.x + ql[ii][1]*kv0.y + ql[ii][2]*kv0.z + ql[ii][3]*kv0.w
                     + ql[ii][4]*kv1.x + ql[ii][5]*kv1.y + ql[ii][6]*kv1.z + ql[ii][7]*kv1.w
                     + ql[ii][8]*kv2.x + ql[ii][9]*kv2.y + ql[ii][10]*kv2.z + ql[ii][11]*kv2.w
                     + ql[ii][12]*kv3.x + ql[ii][13]*kv3.y + ql[ii][14]*kv3.z + ql[ii][15]*kv3.w;
            float dd = wql[ii][0]*wv0.x + wql[ii][1]*wv0.y + wql[ii][2]*wv0.z + wql[ii][3]*wv0.w
                     + wql[ii][4]*wv1.x + wql[ii][5]*wv1.y + wql[ii][6]*wv1.z + wql[ii][7]*wv1.w
                     + wql[ii][8]*wv2.x + wql[ii][9]*wv2.y + wql[ii][10]*wv2.z + wql[ii][11]*wv2.w;
            float d2 = sQn[ii] + knj - 2.f*dd;
            lg[ii][m] = W_L * (qk + bias[((size_t)h*NRES + i0+ii)*NRES + j] - gam*d2);
        }
    }

    #pragma unroll
    for (int ii = 0; ii < 4; ++ii) {
        float mx = fmaxf(lg[ii][0], lg[ii][1]);
        #pragma unroll
        for (int d = 32; d > 0; d >>= 1) mx = fmaxf(mx, __shfl_xor(mx, d));
        if (lane == 0) redm[ii][wave] = mx;
    }
    __syncthreads();
    #pragma unroll
    for (int ii = 0; ii < 4; ++ii) {
        float mx = fmaxf(fmaxf(redm[ii][0], redm[ii][1]), fmaxf(redm[ii][2], redm[ii][3]));
        float e0 = __expf(lg[ii][0]-mx), e1 = __expf(lg[ii][1]-mx);
        lg[ii][0] = e0; lg[ii][1] = e1;
        float sm = e0 + e1;
        #pragma unroll
        for (int d = 32; d > 0; d >>= 1) sm += __shfl_xor(sm, d);
        if (lane == 0) reds[ii][wave] = sm;
    }
    __syncthreads();
    #pragma unroll
    for (int ii = 0; ii < 4; ++ii) {
        float inv = 1.f / (reds[ii][0]+reds[ii][1]+reds[ii][2]+reds[ii][3]);
        float a0 = lg[ii][0]*inv, a1 = lg[ii][1]*inv;
        att[ii][tid] = a0; att[ii][tid+256] = a1;
        bias[((size_t)h*NRES + i0+ii)*NRES + tid]       = a0;
        bias[((size_t)h*NRES + i0+ii)*NRES + tid + 256] = a1;
    }
    __syncthreads();

    // v_out / o_pt: row loaded once, used for 4 residues
    for (int g = wave; g < 10; g += 4) {
        const float4* row = (g < 4) ? &v_t4[((size_t)h*4 + g)*NRES]
                                    : &wv_t4[((size_t)h*6 + (g-4))*NRES];
        float px[4], py[4], pz[4], pw[4];
        #pragma unroll
        for (int ii = 0; ii < 4; ++ii) { px[ii]=0; py[ii]=0; pz[ii]=0; pw[ii]=0; }
        #pragma unroll
        for (int u = 0; u < 8; ++u) {
            int jr = lane + u*64;
            float4 r = row[jr];
            #pragma unroll
            for (int ii = 0; ii < 4; ++ii) {
                float a = att[ii][jr];
                px[ii] += a*r.x; py[ii] += a*r.y; pz[ii] += a*r.z; pw[ii] += a*r.w;
            }
        }
        #pragma unroll
        for (int ii = 0; ii < 4; ++ii) {
            #pragma unroll
            for (int d = 32; d > 0; d >>= 1) {
                px[ii] += __shfl_down(px[ii], d);
                py[ii] += __shfl_down(py[ii], d);
                pz[ii] += __shfl_down(pz[ii], d);
                pw[ii] += __shfl_down(pw[ii], d);
            }
        }
        if (lane == 0) {
            #pragma unroll
            for (int ii = 0; ii < 4; ++ii) {
                if (g < 4) {
                    *reinterpret_cast<float4*>(&cat[(size_t)(i0+ii)*CATF + h*16 + g*4]) =
                        make_float4(px[ii], py[ii], pz[ii], pw[ii]);
                } else {
                    int e = (g-4)*4;
                    optl[ii][e] = px[ii]; optl[ii][e+1] = py[ii];
                    optl[ii][e+2] = pz[ii]; optl[ii][e+3] = pw[ii];
                }
            }
        }
    }
    __syncthreads();

    if (tid < 32) {
        int ii = tid >> 3, p = tid & 7;
        int i = i0 + ii;
        float t0 = T[i*16 + 0*4 + 3], t1 = T[i*16 + 1*4 + 3], t2 = T[i*16 + 2*4 + 3];
        float y0 = optl[ii][p*3+0] - t0, y1 = optl[ii][p*3+1] - t1, y2 = optl[ii][p*3+2] - t2;
        float n2 = 0.f;
        #pragma unroll
        for (int x = 0; x < 3; ++x) {
            float w = T[i*16 + 0*4 + x]*y0 + T[i*16 + 1*4 + x]*y1 + T[i*16 + 2*4 + x]*y2;
            cat[(size_t)i*CATF + 192 + x*96 + h*8 + p] = w;
            n2 += w*w;
        }
        cat[(size_t)i*CATF + 480 + h*8 + p] = sqrtf(n2);
    }
}

// ---------------- Kernel 4: pairwise = att @ z -> cat[576:2112] ----------------
__global__ __launch_bounds__(512) void k_pair(
    const float* __restrict__ z, const float* __restrict__ att,
    float* __restrict__ cat)
{
    int i = blockIdx.x, tid = threadIdx.x;
    int us = tid >> 7, ht = (tid >> 5) & 3, c4 = tid & 31;
    __shared__ float al[12*NRES];     // att, then reused as partial buffer

    for (int idx = tid; idx < 12*NRES; idx += 512) {
        int h = idx >> 9, j = idx & 511;
        al[idx] = att[((size_t)h*NRES + i)*NRES + j];
    }
    __syncthreads();

    const float4* z4 = reinterpret_cast<const float4*>(z + (size_t)i*NRES*CZ);
    float4 a0 = {0,0,0,0}, a1 = {0,0,0,0}, a2 = {0,0,0,0};
    int ub = us*128;
    #pragma unroll 4
    for (int u = 0; u < 128; ++u) {
        int jr = ub + u;
        float4 zv = z4[(size_t)jr*32 + c4];
        float w0 = al[(ht    )*NRES + jr];
        float w1 = al[(ht + 4)*NRES + jr];
        float w2 = al[(ht + 8)*NRES + jr];
        a0.x = fmaf(w0, zv.x, a0.x); a0.y = fmaf(w0, zv.y, a0.y);
        a0.z = fmaf(w0, zv.z, a0.z); a0.w = fmaf(w0, zv.w, a0.w);
        a1.x = fmaf(w1, zv.x, a1.x); a1.y = fmaf(w1, zv.y, a1.y);
        a1.z = fmaf(w1, zv.z, a1.z); a1.w = fmaf(w1, zv.w, a1.w);
        a2.x = fmaf(w2, zv.x, a2.x); a2.y = fmaf(w2, zv.y, a2.y);
        a2.z = fmaf(w2, zv.z, a2.z); a2.w = fmaf(w2, zv.w, a2.w);
    }
    __syncthreads();   // al reads done; reuse as partial buffer
    float* pr = al;    // [512 threads][12]
    {
        float* p = &pr[tid*12];
        p[0]=a0.x; p[1]=a0.y; p[2]=a0.z;  p[3]=a0.w;
        p[4]=a1.x; p[5]=a1.y; p[6]=a1.z;  p[7]=a1.w;
        p[8]=a2.x; p[9]=a2.y; p[10]=a2.z; p[11]=a2.w;
    }
    __syncthreads();

    for (int idx = tid; idx < 1536; idx += 512) {
        int h = idx >> 7, c = idx & 127;
        int hh = h & 3, m = h >> 2, cc4 = c >> 2, x = c & 3;
        float v = 0.f;
        #pragma unroll
        for (int uu = 0; uu < 4; ++uu)
            v += pr[(((uu*4 + hh)*32 + cc4))*12 + m*4 + x];
        cat[(size_t)i*CATF + 576 + h*128 + c] = v;
    }
}

// ---------------- Kernel 5a: split-K Wo GEMM (scalar cat operands, no LDS) ----------------
__global__ __launch_bounds__(384) void k_wo(
    const float* __restrict__ cat, const float* __restrict__ Wo,
    float* __restrict__ part)
{
    int i0 = blockIdx.x * WO_I;
    int fs = blockIdx.y;
    int f0 = fs * FCHUNK;
    int tid = threadIdx.x;
    const float* crow = cat + (size_t)i0*CATF + f0;
    float acc[WO_I];
    #pragma unroll
    for (int j = 0; j < WO_I; ++j) acc[j] = 0.f;
    const float* wp = Wo + (size_t)f0*CS + tid;
    #pragma unroll 4
    for (int f = 0; f < FCHUNK; ++f) {
        float w = wp[(size_t)f*CS];
        #pragma unroll
        for (int j = 0; j < WO_I; ++j)
            acc[j] = fmaf(w, crow[(size_t)j*CATF + f], acc[j]);
    }
    #pragma unroll
    for (int j = 0; j < WO_I; ++j)
        part[((size_t)fs*NRES + i0 + j)*CS + tid] = acc[j];
}

// ---------------- Kernel 5b: reduce partials + bias ----------------
__global__ __launch_bounds__(384) void k_red(
    const float* __restrict__ part, const float* __restrict__ bo,
    float* __restrict__ out)
{
    int i = blockIdx.x, o = threadIdx.x;
    float a = bo[o];
    #pragma unroll
    for (int s = 0; s < FSPLIT; ++s)
        a += part[((size_t)s*NRES + i)*CS + o];
    out[(size_t)i*CS + o] = a;
}

// ---------------- launch ----------------
extern "C" void kernel_launch(void* const* d_in, const int* in_sizes, int n_in,
                              void* d_out, int out_size, void* d_ws, size_t ws_size,
                              hipStream_t stream)
{
    const float* s   = (const float*)d_in[0];
    const float* z   = (const float*)d_in[1];
    const float* T   = (const float*)d_in[2];
    const float* Wq  = (const float*)d_in[3];  const float* bq  = (const float*)d_in[4];
    const float* Wk  = (const float*)d_in[5];  const float* bk  = (const float*)d_in[6];
    const float* Wv  = (const float*)d_in[7];  const float* bv  = (const float*)d_in[8];
    const float* Wqp = (const float*)d_in[9];  const float* bqp = (const float*)d_in[10];
    const float* Wkp = (const float*)d_in[11]; const float* bkp = (const float*)d_in[12];
    const float* Wvp = (const float*)d_in[13]; const float* bvp = (const float*)d_in[14];
    const float* Wb  = (const float*)d_in[15]; const float* bb  = (const float*)d_in[16];
    const float* Wo  = (const float*)d_in[17]; const float* bo  = (const float*)d_in[18];
    const float* hw  = (const float*)d_in[19];
    float* out = (float*)d_out;
    float* ws  = (float*)d_ws;

    size_t off = 0;
    float* q_s  = ws + off; off += (size_t)NH*NRES*CC;
    float* k_t  = ws + off; off += (size_t)NH*NRES*CC;
    float* v_t  = ws + off; off += (size_t)NH*NRES*CC;
    float* wq   = ws + off; off += (size_t)NH*NRES*12;
    float* wk_t = ws + off; off += (size_t)NH*NRES*12;
    float* wv_t = ws + off; off += (size_t)NH*NRES*24;
    float* qn   = ws + off; off += (size_t)NH*NRES;
    float* kn   = ws + off; off += (size_t)NH*NRES;
    float* bias = ws + off; off += (size_t)NH*NRES*NRES;
    float* cat  = ws + off; off += (size_t)NRES*CATF;
    float* part = ws + off; off += (size_t)FSPLIT*NRES*CS;
    float* praw = ws + off; off += (size_t)NRES*FTOT;

    k_gemm<<<dim3(NRES/4, 3), dim3(384), 0, stream>>>(
        s, Wq, bq, Wk, bk, Wv, bv, Wqp, bqp, Wkp, bkp, Wvp, bvp, praw);

    k_post<<<dim3(NRES), dim3(256), 0, stream>>>(
        praw, T, q_s, (float4*)k_t, (float4*)v_t, wq, (float4*)wk_t, (float4*)wv_t, qn, kn);

    k_bias<<<dim3(8, NRES), dim3(256), 0, stream>>>(z, Wb, bb, bias);

    k_att<<<dim3(NRES/4, NH), dim3(256), 0, stream>>>(
        q_s, (const float4*)k_t, wq, (const float4*)wk_t, qn, kn, hw, T, bias,
        (const float4*)v_t, (const float4*)wv_t, cat);

    k_pair<<<dim3(NRES), dim3(512), 0, stream>>>(z, bias, cat);

    k_wo<<<dim3(NRES/WO_I, FSPLIT), dim3(384), 0, stream>>>(cat, Wo, part);

    k_red<<<dim3(NRES), dim3(384), 0, stream>>>(part, bo, out);
}

// Round 15
// 160.676 us; speedup vs baseline: 1.3493x; 1.1071x over previous
//
#include <hip/hip_runtime.h>
#include <hip/hip_bf16.h>
#include <math.h>

// Problem constants
#define NRES 512
#define CS 384
#define CZ 128
#define NH 12
#define CC 16
#define NQP 4
#define NPV 8
#define HC (NH*CC)        // 192
#define FTOT 1152         // 192*3 + 144*2 + 288
#define CATF 2112         // 192 + 288 + 96 + 1536
#define FSPLIT 8
#define FCHUNK 264        // 2112/8
#define W_C 0.23570226039551584f   // sqrt(2/(9*4))
#define W_L 0.5773502691896258f    // sqrt(1/3)

// ---------------- Kernel 1a: all projections as one GEMM ----------------
// grid (128, 3): 4 residues/block.
__global__ __launch_bounds__(384) void k_gemm(
    const float* __restrict__ s,
    const float* __restrict__ Wq, const float* __restrict__ bq,
    const float* __restrict__ Wk, const float* __restrict__ bk,
    const float* __restrict__ Wv, const float* __restrict__ bv,
    const float* __restrict__ Wqp, const float* __restrict__ bqp,
    const float* __restrict__ Wkp, const float* __restrict__ bkp,
    const float* __restrict__ Wvp, const float* __restrict__ bvp,
    float* __restrict__ p_raw)
{
    int r0 = blockIdx.x * 4;
    int f  = blockIdx.y * 384 + threadIdx.x;
    const float* W; const float* bia; int col; int stride;
    if      (f < 192) { W = Wq;  bia = bq;  col = f;       stride = 192; }
    else if (f < 384) { W = Wk;  bia = bk;  col = f - 192; stride = 192; }
    else if (f < 576) { W = Wv;  bia = bv;  col = f - 384; stride = 192; }
    else if (f < 720) { W = Wqp; bia = bqp; col = f - 576; stride = 144; }
    else if (f < 864) { W = Wkp; bia = bkp; col = f - 720; stride = 144; }
    else              { W = Wvp; bia = bvp; col = f - 864; stride = 288; }

    float acc[4];
    float b0 = bia[col];
    #pragma unroll
    for (int j = 0; j < 4; ++j) acc[j] = b0;

    const float* srow = s + (size_t)r0 * CS;
    #pragma unroll 4
    for (int i = 0; i < CS; ++i) {
        float w = W[(size_t)i * stride + col];
        #pragma unroll
        for (int j = 0; j < 4; ++j) acc[j] = fmaf(w, srow[j*CS + i], acc[j]);
    }
    #pragma unroll
    for (int j = 0; j < 4; ++j) p_raw[(size_t)(r0 + j)*FTOT + f] = acc[j];
}

// ---------------- Kernel 1b: warp + transpose layouts ----------------
__global__ __launch_bounds__(256) void k_post(
    const float* __restrict__ p_raw, const float* __restrict__ T,
    float* __restrict__ q_s, float4* __restrict__ k_t4, float4* __restrict__ v_t4,
    float* __restrict__ wq, float4* __restrict__ wk_t4, float4* __restrict__ wv_t4,
    float* __restrict__ qn, float* __restrict__ kn)
{
    int n = blockIdx.x;
    int tid = threadIdx.x;
    __shared__ float pl[FTOT];
    __shared__ float Rl[9], tl[3];
    __shared__ float wq_l[144], wk_l[144], wv_l[288];
    __shared__ float sq_part[48], sk_part[48];

    for (int idx = tid; idx < FTOT/4; idx += 256)
        *reinterpret_cast<float4*>(&pl[idx*4]) =
            *reinterpret_cast<const float4*>(&p_raw[(size_t)n*FTOT + idx*4]);
    if (tid < 9)  Rl[tid] = T[n*16 + (tid/3)*4 + (tid%3)];
    if (tid >= 16 && tid < 19) tl[tid-16] = T[n*16 + (tid-16)*4 + 3];
    __syncthreads();

    if (tid < 48) {
        int h = tid >> 2, p = tid & 3;
        float qy0 = pl[576 + 0*48 + h*4 + p], qy1 = pl[576 + 1*48 + h*4 + p], qy2 = pl[576 + 2*48 + h*4 + p];
        float ky0 = pl[720 + 0*48 + h*4 + p], ky1 = pl[720 + 1*48 + h*4 + p], ky2 = pl[720 + 2*48 + h*4 + p];
        float qs2 = 0.f, ks2 = 0.f;
        #pragma unroll
        for (int x = 0; x < 3; ++x) {
            float wqv = Rl[x*3+0]*qy0 + Rl[x*3+1]*qy1 + Rl[x*3+2]*qy2 + tl[x];
            float wkv = Rl[x*3+0]*ky0 + Rl[x*3+1]*ky1 + Rl[x*3+2]*ky2 + tl[x];
            wq_l[h*12 + p*3 + x] = wqv;
            wk_l[h*12 + p*3 + x] = wkv;
            qs2 += wqv*wqv; ks2 += wkv*wkv;
        }
        sq_part[tid] = qs2; sk_part[tid] = ks2;
    } else if (tid >= 64 && tid < 160) {
        int u = tid - 64; int h = u >> 3, p = u & 7;
        float y0 = pl[864 + 0*96 + h*8 + p], y1 = pl[864 + 1*96 + h*8 + p], y2 = pl[864 + 2*96 + h*8 + p];
        #pragma unroll
        for (int x = 0; x < 3; ++x) {
            wv_l[h*24 + p*3 + x] = Rl[x*3+0]*y0 + Rl[x*3+1]*y1 + Rl[x*3+2]*y2 + tl[x];
        }
    }
    __syncthreads();

    if (tid < 48) {
        int h = tid >> 2, c4 = tid & 3;
        float4 qv = *reinterpret_cast<const float4*>(&pl[h*16 + c4*4]);
        qv.x *= 0.25f; qv.y *= 0.25f; qv.z *= 0.25f; qv.w *= 0.25f;
        float4 kv = *reinterpret_cast<const float4*>(&pl[192 + h*16 + c4*4]);
        float4 vv = *reinterpret_cast<const float4*>(&pl[384 + h*16 + c4*4]);
        *reinterpret_cast<float4*>(&q_s[((size_t)h*NRES + n)*16 + c4*4]) = qv;
        k_t4[((size_t)h*4 + c4)*NRES + n] = kv;
        v_t4[((size_t)h*4 + c4)*NRES + n] = vv;
    } else if (tid >= 64 && tid < 100) {
        int u = tid - 64; int h = u / 3, e4 = u % 3;
        float4 kv = *reinterpret_cast<const float4*>(&wk_l[h*12 + e4*4]);
        wk_t4[((size_t)h*3 + e4)*NRES + n] = kv;
    } else if (tid >= 104 && tid < 140) {
        int u = tid - 104; int h = u / 3, e4 = u % 3;
        float4 qv = *reinterpret_cast<const float4*>(&wq_l[h*12 + e4*4]);
        *reinterpret_cast<float4*>(&wq[((size_t)h*NRES + n)*12 + e4*4]) = qv;
    } else if (tid >= 160 && tid < 232) {
        int u = tid - 160; int h = u / 6, e4 = u % 6;
        float4 vv = *reinterpret_cast<const float4*>(&wv_l[h*24 + e4*4]);
        wv_t4[((size_t)h*6 + e4)*NRES + n] = vv;
    } else if (tid >= 232 && tid < 244) {
        int h = tid - 232;
        qn[(size_t)h*NRES + n] = sq_part[h*4] + sq_part[h*4+1] + sq_part[h*4+2] + sq_part[h*4+3];
        kn[(size_t)h*NRES + n] = sk_part[h*4] + sk_part[h*4+1] + sk_part[h*4+2] + sk_part[h*4+3];
    }
}

// ---------------- Kernel 2: bias = z @ Wb + bb  -> [H][N][N] ----------------
// (R12 version: coalesced z->LDS once; Wb via scalar s_load path)
__global__ __launch_bounds__(256) void k_bias(
    const float* __restrict__ z, const float* __restrict__ Wb,
    const float* __restrict__ bb, float* __restrict__ bias)
{
    int j0 = blockIdx.x * 64, i = blockIdx.y;
    int tid = threadIdx.x;
    int r = tid & 63, p = tid >> 6;   // p = wave index (0..3)
    __shared__ float zl[64*132];
    __shared__ float partial[4][12][64];
    __shared__ float bbl[12];

    if (tid < 12) bbl[tid] = bb[tid];
    const float4* zsrc = reinterpret_cast<const float4*>(z + ((size_t)i*NRES + j0)*CZ);
    #pragma unroll
    for (int it = 0; it < 8; ++it) {
        int idx = it*256 + tid;
        int j = idx >> 5, c4 = idx & 31;
        *reinterpret_cast<float4*>(&zl[j*132 + c4*4]) = zsrc[idx];
    }
    __syncthreads();

    float acc[12] = {0,0,0,0,0,0,0,0,0,0,0,0};
    for (int it = 0; it < 8; ++it) {
        int c4 = __builtin_amdgcn_readfirstlane(p*8 + it);   // wave-uniform
        const float* wb = Wb + c4*48;
        float4 zv = *reinterpret_cast<const float4*>(&zl[r*132 + c4*4]);
        #pragma unroll
        for (int h = 0; h < 12; ++h) {
            acc[h] = fmaf(zv.x, wb[h],
                     fmaf(zv.y, wb[12+h],
                     fmaf(zv.z, wb[24+h],
                     fmaf(zv.w, wb[36+h], acc[h]))));
        }
    }
    #pragma unroll
    for (int h = 0; h < 12; ++h) partial[p][h][r] = acc[h];
    __syncthreads();

    #pragma unroll
    for (int u = 0; u < 3; ++u) {
        int idx = u*256 + tid;
        int h = idx >> 6, rr = idx & 63;
        float v = partial[0][h][rr] + partial[1][h][rr]
                + partial[2][h][rr] + partial[3][h][rr] + bbl[h];
        bias[((size_t)h*NRES + i)*NRES + j0 + rr] = v;
    }
}

// ------- Kernel 3: att softmax for 4 residues/block (k/v rows loaded once) -------
__global__ __launch_bounds__(256) void k_att(
    const float* __restrict__ q_s, const float4* __restrict__ k_t4,
    const float* __restrict__ wq, const float4* __restrict__ wk_t4,
    const float* __restrict__ qn, const float* __restrict__ kn,
    const float* __restrict__ hw, const float* __restrict__ T,
    float* __restrict__ bias,       // in: bias, out: att
    const float4* __restrict__ v_t4, const float4* __restrict__ wv_t4,
    float* __restrict__ cat)
{
    int i0 = blockIdx.x * 4, h = blockIdx.y;
    int tid = threadIdx.x;
    int wave = tid >> 6, lane = tid & 63;
    __shared__ float ql[4][16], wql[4][12];
    __shared__ float att[4][NRES];
    __shared__ float redm[4][4], reds[4][4];
    __shared__ float optl[4][24];
    __shared__ float sQn[4], sG;

    if (tid < 64) {
        int ii = tid >> 4, c = tid & 15;
        ql[ii][c] = q_s[((size_t)h*NRES + i0+ii)*16 + c];
    } else if (tid < 112) {
        int u = tid - 64; int ii = u / 12, e = u % 12;
        wql[ii][e] = wq[((size_t)h*NRES + i0+ii)*12 + e];
    } else if (tid < 116) {
        int ii = tid - 112;
        sQn[ii] = qn[(size_t)h*NRES + i0+ii];
    } else if (tid == 116) {
        float x = hw[h];
        float sp = (x > 20.f) ? x : log1pf(expf(x));
        sG = sp * W_C * 0.5f;
    }
    __syncthreads();
    float gam = sG;

    float lg[4][2];
    #pragma unroll
    for (int m = 0; m < 2; ++m) {
        int j = tid + m*256;
        float4 kv0 = k_t4[((size_t)h*4 + 0)*NRES + j];
        float4 kv1 = k_t4[((size_t)h*4 + 1)*NRES + j];
        float4 kv2 = k_t4[((size_t)h*4 + 2)*NRES + j];
        float4 kv3 = k_t4[((size_t)h*4 + 3)*NRES + j];
        float4 wv0 = wk_t4[((size_t)h*3 + 0)*NRES + j];
        float4 wv1 = wk_t4[((size_t)h*3 + 1)*NRES + j];
        float4 wv2 = wk_t4[((size_t)h*3 + 2)*NRES + j];
        float knj = kn[(size_t)h*NRES + j];
        #pragma unroll
        for (int ii = 0; ii < 4; ++ii) {
            float qk = ql[ii][0]*kv0.x + ql[ii][1]*kv0.y + ql[ii][2]*kv0.z + ql[ii][3]*kv0.w
                     + ql[ii][4]*kv1.x + ql[ii][5]*kv1.y + ql[ii][6]*kv1.z + ql[ii][7]*kv1.w
                     + ql[ii][8]*kv2.x + ql[ii][9]*kv2.y + ql[ii][10]*kv2.z + ql[ii][11]*kv2.w
                     + ql[ii][12]*kv3.x + ql[ii][13]*kv3.y + ql[ii][14]*kv3.z + ql[ii][15]*kv3.w;
            float dd = wql[ii][0]*wv0.x + wql[ii][1]*wv0.y + wql[ii][2]*wv0.z + wql[ii][3]*wv0.w
                     + wql[ii][4]*wv1.x + wql[ii][5]*wv1.y + wql[ii][6]*wv1.z + wql[ii][7]*wv1.w
                     + wql[ii][8]*wv2.x + wql[ii][9]*wv2.y + wql[ii][10]*wv2.z + wql[ii][11]*wv2.w;
            float d2 = sQn[ii] + knj - 2.f*dd;
            lg[ii][m] = W_L * (qk + bias[((size_t)h*NRES + i0+ii)*NRES + j] - gam*d2);
        }
    }

    #pragma unroll
    for (int ii = 0; ii < 4; ++ii) {
        float mx = fmaxf(lg[ii][0], lg[ii][1]);
        #pragma unroll
        for (int d = 32; d > 0; d >>= 1) mx = fmaxf(mx, __shfl_xor(mx, d));
        if (lane == 0) redm[ii][wave] = mx;
    }
    __syncthreads();
    #pragma unroll
    for (int ii = 0; ii < 4; ++ii) {
        float mx = fmaxf(fmaxf(redm[ii][0], redm[ii][1]), fmaxf(redm[ii][2], redm[ii][3]));
        float e0 = __expf(lg[ii][0]-mx), e1 = __expf(lg[ii][1]-mx);
        lg[ii][0] = e0; lg[ii][1] = e1;
        float sm = e0 + e1;
        #pragma unroll
        for (int d = 32; d > 0; d >>= 1) sm += __shfl_xor(sm, d);
        if (lane == 0) reds[ii][wave] = sm;
    }
    __syncthreads();
    #pragma unroll
    for (int ii = 0; ii < 4; ++ii) {
        float inv = 1.f / (reds[ii][0]+reds[ii][1]+reds[ii][2]+reds[ii][3]);
        float a0 = lg[ii][0]*inv, a1 = lg[ii][1]*inv;
        att[ii][tid] = a0; att[ii][tid+256] = a1;
        bias[((size_t)h*NRES + i0+ii)*NRES + tid]       = a0;
        bias[((size_t)h*NRES + i0+ii)*NRES + tid + 256] = a1;
    }
    __syncthreads();

    // v_out / o_pt: row loaded once, used for 4 residues
    for (int g = wave; g < 10; g += 4) {
        const float4* row = (g < 4) ? &v_t4[((size_t)h*4 + g)*NRES]
                                    : &wv_t4[((size_t)h*6 + (g-4))*NRES];
        float px[4], py[4], pz[4], pw[4];
        #pragma unroll
        for (int ii = 0; ii < 4; ++ii) { px[ii]=0; py[ii]=0; pz[ii]=0; pw[ii]=0; }
        #pragma unroll
        for (int u = 0; u < 8; ++u) {
            int jr = lane + u*64;
            float4 r = row[jr];
            #pragma unroll
            for (int ii = 0; ii < 4; ++ii) {
                float a = att[ii][jr];
                px[ii] += a*r.x; py[ii] += a*r.y; pz[ii] += a*r.z; pw[ii] += a*r.w;
            }
        }
        #pragma unroll
        for (int ii = 0; ii < 4; ++ii) {
            #pragma unroll
            for (int d = 32; d > 0; d >>= 1) {
                px[ii] += __shfl_down(px[ii], d);
                py[ii] += __shfl_down(py[ii], d);
                pz[ii] += __shfl_down(pz[ii], d);
                pw[ii] += __shfl_down(pw[ii], d);
            }
        }
        if (lane == 0) {
            #pragma unroll
            for (int ii = 0; ii < 4; ++ii) {
                if (g < 4) {
                    *reinterpret_cast<float4*>(&cat[(size_t)(i0+ii)*CATF + h*16 + g*4]) =
                        make_float4(px[ii], py[ii], pz[ii], pw[ii]);
                } else {
                    int e = (g-4)*4;
                    optl[ii][e] = px[ii]; optl[ii][e+1] = py[ii];
                    optl[ii][e+2] = pz[ii]; optl[ii][e+3] = pw[ii];
                }
            }
        }
    }
    __syncthreads();

    if (tid < 32) {
        int ii = tid >> 3, p = tid & 7;
        int i = i0 + ii;
        float t0 = T[i*16 + 0*4 + 3], t1 = T[i*16 + 1*4 + 3], t2 = T[i*16 + 2*4 + 3];
        float y0 = optl[ii][p*3+0] - t0, y1 = optl[ii][p*3+1] - t1, y2 = optl[ii][p*3+2] - t2;
        float n2 = 0.f;
        #pragma unroll
        for (int x = 0; x < 3; ++x) {
            float w = T[i*16 + 0*4 + x]*y0 + T[i*16 + 1*4 + x]*y1 + T[i*16 + 2*4 + x]*y2;
            cat[(size_t)i*CATF + 192 + x*96 + h*8 + p] = w;
            n2 += w*w;
        }
        cat[(size_t)i*CATF + 480 + h*8 + p] = sqrtf(n2);
    }
}

// ---------------- Kernel 4: pairwise = att @ z -> cat[576:2112] ----------------
__global__ __launch_bounds__(512) void k_pair(
    const float* __restrict__ z, const float* __restrict__ att,
    float* __restrict__ cat)
{
    int i = blockIdx.x, tid = threadIdx.x;
    int us = tid >> 7, ht = (tid >> 5) & 3, c4 = tid & 31;
    __shared__ float al[12*NRES];     // att, then reused as partial buffer

    for (int idx = tid; idx < 12*NRES; idx += 512) {
        int h = idx >> 9, j = idx & 511;
        al[idx] = att[((size_t)h*NRES + i)*NRES + j];
    }
    __syncthreads();

    const float4* z4 = reinterpret_cast<const float4*>(z + (size_t)i*NRES*CZ);
    float4 a0 = {0,0,0,0}, a1 = {0,0,0,0}, a2 = {0,0,0,0};
    int ub = us*128;
    #pragma unroll 4
    for (int u = 0; u < 128; ++u) {
        int jr = ub + u;
        float4 zv = z4[(size_t)jr*32 + c4];
        float w0 = al[(ht    )*NRES + jr];
        float w1 = al[(ht + 4)*NRES + jr];
        float w2 = al[(ht + 8)*NRES + jr];
        a0.x = fmaf(w0, zv.x, a0.x); a0.y = fmaf(w0, zv.y, a0.y);
        a0.z = fmaf(w0, zv.z, a0.z); a0.w = fmaf(w0, zv.w, a0.w);
        a1.x = fmaf(w1, zv.x, a1.x); a1.y = fmaf(w1, zv.y, a1.y);
        a1.z = fmaf(w1, zv.z, a1.z); a1.w = fmaf(w1, zv.w, a1.w);
        a2.x = fmaf(w2, zv.x, a2.x); a2.y = fmaf(w2, zv.y, a2.y);
        a2.z = fmaf(w2, zv.z, a2.z); a2.w = fmaf(w2, zv.w, a2.w);
    }
    __syncthreads();   // al reads done; reuse as partial buffer
    float* pr = al;    // [512 threads][12]
    {
        float* p = &pr[tid*12];
        p[0]=a0.x; p[1]=a0.y; p[2]=a0.z;  p[3]=a0.w;
        p[4]=a1.x; p[5]=a1.y; p[6]=a1.z;  p[7]=a1.w;
        p[8]=a2.x; p[9]=a2.y; p[10]=a2.z; p[11]=a2.w;
    }
    __syncthreads();

    for (int idx = tid; idx < 1536; idx += 512) {
        int h = idx >> 7, c = idx & 127;
        int hh = h & 3, m = h >> 2, cc4 = c >> 2, x = c & 3;
        float v = 0.f;
        #pragma unroll
        for (int uu = 0; uu < 4; ++uu)
            v += pr[(((uu*4 + hh)*32 + cc4))*12 + m*4 + x];
        cat[(size_t)i*CATF + 576 + h*128 + c] = v;
    }
}

// ---------------- Kernel 5a: split-K Wo GEMM (R12 LDS version) ----------------
__global__ __launch_bounds__(384) void k_wo(
    const float* __restrict__ cat, const float* __restrict__ Wo,
    float* __restrict__ part)
{
    int i0 = blockIdx.x * 8;
    int fs = blockIdx.y;
    int f0 = fs * FCHUNK;
    int tid = threadIdx.x;
    __shared__ float cl[8][FCHUNK];
    for (int idx = tid; idx < 8*(FCHUNK/4); idx += 384) {
        int j = idx / (FCHUNK/4), q = idx % (FCHUNK/4);
        *reinterpret_cast<float4*>(&cl[j][q*4]) =
            *reinterpret_cast<const float4*>(&cat[(size_t)(i0+j)*CATF + f0 + q*4]);
    }
    __syncthreads();
    float acc[8] = {0,0,0,0,0,0,0,0};
    const float* wp = Wo + (size_t)f0*CS + tid;
    #pragma unroll 4
    for (int f = 0; f < FCHUNK; ++f) {
        float w = wp[(size_t)f*CS];
        #pragma unroll
        for (int j = 0; j < 8; ++j) acc[j] = fmaf(w, cl[j][f], acc[j]);
    }
    #pragma unroll
    for (int j = 0; j < 8; ++j)
        part[((size_t)fs*NRES + i0 + j)*CS + tid] = acc[j];
}

// ---------------- Kernel 5b: reduce partials + bias ----------------
__global__ __launch_bounds__(384) void k_red(
    const float* __restrict__ part, const float* __restrict__ bo,
    float* __restrict__ out)
{
    int i = blockIdx.x, o = threadIdx.x;
    float a = bo[o];
    #pragma unroll
    for (int s = 0; s < FSPLIT; ++s)
        a += part[((size_t)s*NRES + i)*CS + o];
    out[(size_t)i*CS + o] = a;
}

// ---------------- launch ----------------
extern "C" void kernel_launch(void* const* d_in, const int* in_sizes, int n_in,
                              void* d_out, int out_size, void* d_ws, size_t ws_size,
                              hipStream_t stream)
{
    const float* s   = (const float*)d_in[0];
    const float* z   = (const float*)d_in[1];
    const float* T   = (const float*)d_in[2];
    const float* Wq  = (const float*)d_in[3];  const float* bq  = (const float*)d_in[4];
    const float* Wk  = (const float*)d_in[5];  const float* bk  = (const float*)d_in[6];
    const float* Wv  = (const float*)d_in[7];  const float* bv  = (const float*)d_in[8];
    const float* Wqp = (const float*)d_in[9];  const float* bqp = (const float*)d_in[10];
    const float* Wkp = (const float*)d_in[11]; const float* bkp = (const float*)d_in[12];
    const float* Wvp = (const float*)d_in[13]; const float* bvp = (const float*)d_in[14];
    const float* Wb  = (const float*)d_in[15]; const float* bb  = (const float*)d_in[16];
    const float* Wo  = (const float*)d_in[17]; const float* bo  = (const float*)d_in[18];
    const float* hw  = (const float*)d_in[19];
    float* out = (float*)d_out;
    float* ws  = (float*)d_ws;

    size_t off = 0;
    float* q_s  = ws + off; off += (size_t)NH*NRES*CC;
    float* k_t  = ws + off; off += (size_t)NH*NRES*CC;
    float* v_t  = ws + off; off += (size_t)NH*NRES*CC;
    float* wq   = ws + off; off += (size_t)NH*NRES*12;
    float* wk_t = ws + off; off += (size_t)NH*NRES*12;
    float* wv_t = ws + off; off += (size_t)NH*NRES*24;
    float* qn   = ws + off; off += (size_t)NH*NRES;
    float* kn   = ws + off; off += (size_t)NH*NRES;
    float* bias = ws + off; off += (size_t)NH*NRES*NRES;
    float* cat  = ws + off; off += (size_t)NRES*CATF;
    float* part = ws + off; off += (size_t)FSPLIT*NRES*CS;
    float* praw = ws + off; off += (size_t)NRES*FTOT;

    k_gemm<<<dim3(NRES/4, 3), dim3(384), 0, stream>>>(
        s, Wq, bq, Wk, bk, Wv, bv, Wqp, bqp, Wkp, bkp, Wvp, bvp, praw);

    k_post<<<dim3(NRES), dim3(256), 0, stream>>>(
        praw, T, q_s, (float4*)k_t, (float4*)v_t, wq, (float4*)wk_t, (float4*)wv_t, qn, kn);

    k_bias<<<dim3(8, NRES), dim3(256), 0, stream>>>(z, Wb, bb, bias);

    k_att<<<dim3(NRES/4, NH), dim3(256), 0, stream>>>(
        q_s, (const float4*)k_t, wq, (const float4*)wk_t, qn, kn, hw, T, bias,
        (const float4*)v_t, (const float4*)wv_t, cat);

    k_pair<<<dim3(NRES), dim3(512), 0, stream>>>(z, bias, cat);

    k_wo<<<dim3(NRES/8, FSPLIT), dim3(384), 0, stream>>>(cat, Wo, part);

    k_red<<<dim3(NRES), dim3(384), 0, stream>>>(part, bo, out);
}

// Round 16
// 155.753 us; speedup vs baseline: 1.3920x; 1.0316x over previous
//
#include <hip/hip_runtime.h>
#include <hip/hip_bf16.h>
#include <math.h>

// Problem constants
#define NRES 512
#define CS 384
#define CZ 128
#define NH 12
#define CC 16
#define NQP 4
#define NPV 8
#define HC (NH*CC)        // 192
#define FTOT 1152         // 192*3 + 144*2 + 288
#define CATF 2112         // 192 + 288 + 96 + 1536
#define FSPLIT 8
#define FCHUNK 264        // 2112/8
#define W_C 0.23570226039551584f   // sqrt(2/(9*4))
#define W_L 0.5773502691896258f    // sqrt(1/3)

// ---------------- Kernel 1a: all projections as one GEMM ----------------
// grid (128, 3): 4 residues/block.
__global__ __launch_bounds__(384) void k_gemm(
    const float* __restrict__ s,
    const float* __restrict__ Wq, const float* __restrict__ bq,
    const float* __restrict__ Wk, const float* __restrict__ bk,
    const float* __restrict__ Wv, const float* __restrict__ bv,
    const float* __restrict__ Wqp, const float* __restrict__ bqp,
    const float* __restrict__ Wkp, const float* __restrict__ bkp,
    const float* __restrict__ Wvp, const float* __restrict__ bvp,
    float* __restrict__ p_raw)
{
    int r0 = blockIdx.x * 4;
    int f  = blockIdx.y * 384 + threadIdx.x;
    const float* W; const float* bia; int col; int stride;
    if      (f < 192) { W = Wq;  bia = bq;  col = f;       stride = 192; }
    else if (f < 384) { W = Wk;  bia = bk;  col = f - 192; stride = 192; }
    else if (f < 576) { W = Wv;  bia = bv;  col = f - 384; stride = 192; }
    else if (f < 720) { W = Wqp; bia = bqp; col = f - 576; stride = 144; }
    else if (f < 864) { W = Wkp; bia = bkp; col = f - 720; stride = 144; }
    else              { W = Wvp; bia = bvp; col = f - 864; stride = 288; }

    float acc[4];
    float b0 = bia[col];
    #pragma unroll
    for (int j = 0; j < 4; ++j) acc[j] = b0;

    const float* srow = s + (size_t)r0 * CS;
    #pragma unroll 4
    for (int i = 0; i < CS; ++i) {
        float w = W[(size_t)i * stride + col];
        #pragma unroll
        for (int j = 0; j < 4; ++j) acc[j] = fmaf(w, srow[j*CS + i], acc[j]);
    }
    #pragma unroll
    for (int j = 0; j < 4; ++j) p_raw[(size_t)(r0 + j)*FTOT + f] = acc[j];
}

// ---------------- Kernel 1b: warp + transpose layouts ----------------
__global__ __launch_bounds__(256) void k_post(
    const float* __restrict__ p_raw, const float* __restrict__ T,
    float* __restrict__ q_s, float4* __restrict__ k_t4, float4* __restrict__ v_t4,
    float* __restrict__ wq, float4* __restrict__ wk_t4, float4* __restrict__ wv_t4,
    float* __restrict__ qn, float* __restrict__ kn)
{
    int n = blockIdx.x;
    int tid = threadIdx.x;
    __shared__ float pl[FTOT];
    __shared__ float Rl[9], tl[3];
    __shared__ float wq_l[144], wk_l[144], wv_l[288];
    __shared__ float sq_part[48], sk_part[48];

    for (int idx = tid; idx < FTOT/4; idx += 256)
        *reinterpret_cast<float4*>(&pl[idx*4]) =
            *reinterpret_cast<const float4*>(&p_raw[(size_t)n*FTOT + idx*4]);
    if (tid < 9)  Rl[tid] = T[n*16 + (tid/3)*4 + (tid%3)];
    if (tid >= 16 && tid < 19) tl[tid-16] = T[n*16 + (tid-16)*4 + 3];
    __syncthreads();

    if (tid < 48) {
        int h = tid >> 2, p = tid & 3;
        float qy0 = pl[576 + 0*48 + h*4 + p], qy1 = pl[576 + 1*48 + h*4 + p], qy2 = pl[576 + 2*48 + h*4 + p];
        float ky0 = pl[720 + 0*48 + h*4 + p], ky1 = pl[720 + 1*48 + h*4 + p], ky2 = pl[720 + 2*48 + h*4 + p];
        float qs2 = 0.f, ks2 = 0.f;
        #pragma unroll
        for (int x = 0; x < 3; ++x) {
            float wqv = Rl[x*3+0]*qy0 + Rl[x*3+1]*qy1 + Rl[x*3+2]*qy2 + tl[x];
            float wkv = Rl[x*3+0]*ky0 + Rl[x*3+1]*ky1 + Rl[x*3+2]*ky2 + tl[x];
            wq_l[h*12 + p*3 + x] = wqv;
            wk_l[h*12 + p*3 + x] = wkv;
            qs2 += wqv*wqv; ks2 += wkv*wkv;
        }
        sq_part[tid] = qs2; sk_part[tid] = ks2;
    } else if (tid >= 64 && tid < 160) {
        int u = tid - 64; int h = u >> 3, p = u & 7;
        float y0 = pl[864 + 0*96 + h*8 + p], y1 = pl[864 + 1*96 + h*8 + p], y2 = pl[864 + 2*96 + h*8 + p];
        #pragma unroll
        for (int x = 0; x < 3; ++x) {
            wv_l[h*24 + p*3 + x] = Rl[x*3+0]*y0 + Rl[x*3+1]*y1 + Rl[x*3+2]*y2 + tl[x];
        }
    }
    __syncthreads();

    if (tid < 48) {
        int h = tid >> 2, c4 = tid & 3;
        float4 qv = *reinterpret_cast<const float4*>(&pl[h*16 + c4*4]);
        qv.x *= 0.25f; qv.y *= 0.25f; qv.z *= 0.25f; qv.w *= 0.25f;
        float4 kv = *reinterpret_cast<const float4*>(&pl[192 + h*16 + c4*4]);
        float4 vv = *reinterpret_cast<const float4*>(&pl[384 + h*16 + c4*4]);
        *reinterpret_cast<float4*>(&q_s[((size_t)h*NRES + n)*16 + c4*4]) = qv;
        k_t4[((size_t)h*4 + c4)*NRES + n] = kv;
        v_t4[((size_t)h*4 + c4)*NRES + n] = vv;
    } else if (tid >= 64 && tid < 100) {
        int u = tid - 64; int h = u / 3, e4 = u % 3;
        float4 kv = *reinterpret_cast<const float4*>(&wk_l[h*12 + e4*4]);
        wk_t4[((size_t)h*3 + e4)*NRES + n] = kv;
    } else if (tid >= 104 && tid < 140) {
        int u = tid - 104; int h = u / 3, e4 = u % 3;
        float4 qv = *reinterpret_cast<const float4*>(&wq_l[h*12 + e4*4]);
        *reinterpret_cast<float4*>(&wq[((size_t)h*NRES + n)*12 + e4*4]) = qv;
    } else if (tid >= 160 && tid < 232) {
        int u = tid - 160; int h = u / 6, e4 = u % 6;
        float4 vv = *reinterpret_cast<const float4*>(&wv_l[h*24 + e4*4]);
        wv_t4[((size_t)h*6 + e4)*NRES + n] = vv;
    } else if (tid >= 232 && tid < 244) {
        int h = tid - 232;
        qn[(size_t)h*NRES + n] = sq_part[h*4] + sq_part[h*4+1] + sq_part[h*4+2] + sq_part[h*4+3];
        kn[(size_t)h*NRES + n] = sk_part[h*4] + sk_part[h*4+1] + sk_part[h*4+2] + sk_part[h*4+3];
    }
}

// ---------------- Kernel 2: bias = z @ Wb + bb  -> [H][N][N] ----------------
// (R12 version: coalesced z->LDS once; Wb via scalar s_load path)
__global__ __launch_bounds__(256) void k_bias(
    const float* __restrict__ z, const float* __restrict__ Wb,
    const float* __restrict__ bb, float* __restrict__ bias)
{
    int j0 = blockIdx.x * 64, i = blockIdx.y;
    int tid = threadIdx.x;
    int r = tid & 63, p = tid >> 6;   // p = wave index (0..3)
    __shared__ float zl[64*132];
    __shared__ float partial[4][12][64];
    __shared__ float bbl[12];

    if (tid < 12) bbl[tid] = bb[tid];
    const float4* zsrc = reinterpret_cast<const float4*>(z + ((size_t)i*NRES + j0)*CZ);
    #pragma unroll
    for (int it = 0; it < 8; ++it) {
        int idx = it*256 + tid;
        int j = idx >> 5, c4 = idx & 31;
        *reinterpret_cast<float4*>(&zl[j*132 + c4*4]) = zsrc[idx];
    }
    __syncthreads();

    float acc[12] = {0,0,0,0,0,0,0,0,0,0,0,0};
    for (int it = 0; it < 8; ++it) {
        int c4 = __builtin_amdgcn_readfirstlane(p*8 + it);   // wave-uniform
        const float* wb = Wb + c4*48;
        float4 zv = *reinterpret_cast<const float4*>(&zl[r*132 + c4*4]);
        #pragma unroll
        for (int h = 0; h < 12; ++h) {
            acc[h] = fmaf(zv.x, wb[h],
                     fmaf(zv.y, wb[12+h],
                     fmaf(zv.z, wb[24+h],
                     fmaf(zv.w, wb[36+h], acc[h]))));
        }
    }
    #pragma unroll
    for (int h = 0; h < 12; ++h) partial[p][h][r] = acc[h];
    __syncthreads();

    #pragma unroll
    for (int u = 0; u < 3; ++u) {
        int idx = u*256 + tid;
        int h = idx >> 6, rr = idx & 63;
        float v = partial[0][h][rr] + partial[1][h][rr]
                + partial[2][h][rr] + partial[3][h][rr] + bbl[h];
        bias[((size_t)h*NRES + i)*NRES + j0 + rr] = v;
    }
}

// ------- Kernel 3: att softmax for 2 residues/block (k/v rows loaded once) -------
// att written to bf16 att16 buffer (halves k_pair's read traffic).
__global__ __launch_bounds__(256) void k_att(
    const float* __restrict__ q_s, const float4* __restrict__ k_t4,
    const float* __restrict__ wq, const float4* __restrict__ wk_t4,
    const float* __restrict__ qn, const float* __restrict__ kn,
    const float* __restrict__ hw, const float* __restrict__ T,
    const float* __restrict__ bias,
    __hip_bfloat16* __restrict__ att16,
    const float4* __restrict__ v_t4, const float4* __restrict__ wv_t4,
    float* __restrict__ cat)
{
    int i0 = blockIdx.x * 2, h = blockIdx.y;
    int tid = threadIdx.x;
    int wave = tid >> 6, lane = tid & 63;
    __shared__ float ql[2][16], wql[2][12];
    __shared__ float att[2][NRES];
    __shared__ float redm[2][4], reds[2][4];
    __shared__ float optl[2][24];
    __shared__ float sQn[2], sG;

    if (tid < 32) {
        int ii = tid >> 4, c = tid & 15;
        ql[ii][c] = q_s[((size_t)h*NRES + i0+ii)*16 + c];
    } else if (tid < 56) {
        int u = tid - 32; int ii = u / 12, e = u % 12;
        wql[ii][e] = wq[((size_t)h*NRES + i0+ii)*12 + e];
    } else if (tid < 58) {
        int ii = tid - 56;
        sQn[ii] = qn[(size_t)h*NRES + i0+ii];
    } else if (tid == 58) {
        float x = hw[h];
        float sp = (x > 20.f) ? x : log1pf(expf(x));
        sG = sp * W_C * 0.5f;
    }
    __syncthreads();
    float gam = sG;

    float lg[2][2];
    #pragma unroll
    for (int m = 0; m < 2; ++m) {
        int j = tid + m*256;
        float4 kv0 = k_t4[((size_t)h*4 + 0)*NRES + j];
        float4 kv1 = k_t4[((size_t)h*4 + 1)*NRES + j];
        float4 kv2 = k_t4[((size_t)h*4 + 2)*NRES + j];
        float4 kv3 = k_t4[((size_t)h*4 + 3)*NRES + j];
        float4 wv0 = wk_t4[((size_t)h*3 + 0)*NRES + j];
        float4 wv1 = wk_t4[((size_t)h*3 + 1)*NRES + j];
        float4 wv2 = wk_t4[((size_t)h*3 + 2)*NRES + j];
        float knj = kn[(size_t)h*NRES + j];
        #pragma unroll
        for (int ii = 0; ii < 2; ++ii) {
            float qk = ql[ii][0]*kv0.x + ql[ii][1]*kv0.y + ql[ii][2]*kv0.z + ql[ii][3]*kv0.w
                     + ql[ii][4]*kv1.x + ql[ii][5]*kv1.y + ql[ii][6]*kv1.z + ql[ii][7]*kv1.w
                     + ql[ii][8]*kv2.x + ql[ii][9]*kv2.y + ql[ii][10]*kv2.z + ql[ii][11]*kv2.w
                     + ql[ii][12]*kv3.x + ql[ii][13]*kv3.y + ql[ii][14]*kv3.z + ql[ii][15]*kv3.w;
            float dd = wql[ii][0]*wv0.x + wql[ii][1]*wv0.y + wql[ii][2]*wv0.z + wql[ii][3]*wv0.w
                     + wql[ii][4]*wv1.x + wql[ii][5]*wv1.y + wql[ii][6]*wv1.z + wql[ii][7]*wv1.w
                     + wql[ii][8]*wv2.x + wql[ii][9]*wv2.y + wql[ii][10]*wv2.z + wql[ii][11]*wv2.w;
            float d2 = sQn[ii] + knj - 2.f*dd;
            lg[ii][m] = W_L * (qk + bias[((size_t)h*NRES + i0+ii)*NRES + j] - gam*d2);
        }
    }

    #pragma unroll
    for (int ii = 0; ii < 2; ++ii) {
        float mx = fmaxf(lg[ii][0], lg[ii][1]);
        #pragma unroll
        for (int d = 32; d > 0; d >>= 1) mx = fmaxf(mx, __shfl_xor(mx, d));
        if (lane == 0) redm[ii][wave] = mx;
    }
    __syncthreads();
    #pragma unroll
    for (int ii = 0; ii < 2; ++ii) {
        float mx = fmaxf(fmaxf(redm[ii][0], redm[ii][1]), fmaxf(redm[ii][2], redm[ii][3]));
        float e0 = __expf(lg[ii][0]-mx), e1 = __expf(lg[ii][1]-mx);
        lg[ii][0] = e0; lg[ii][1] = e1;
        float sm = e0 + e1;
        #pragma unroll
        for (int d = 32; d > 0; d >>= 1) sm += __shfl_xor(sm, d);
        if (lane == 0) reds[ii][wave] = sm;
    }
    __syncthreads();
    #pragma unroll
    for (int ii = 0; ii < 2; ++ii) {
        float inv = 1.f / (reds[ii][0]+reds[ii][1]+reds[ii][2]+reds[ii][3]);
        float a0 = lg[ii][0]*inv, a1 = lg[ii][1]*inv;
        att[ii][tid] = a0; att[ii][tid+256] = a1;
        att16[((size_t)h*NRES + i0+ii)*NRES + tid]       = __float2bfloat16(a0);
        att16[((size_t)h*NRES + i0+ii)*NRES + tid + 256] = __float2bfloat16(a1);
    }
    __syncthreads();

    for (int g = wave; g < 10; g += 4) {
        const float4* row = (g < 4) ? &v_t4[((size_t)h*4 + g)*NRES]
                                    : &wv_t4[((size_t)h*6 + (g-4))*NRES];
        float p0x=0,p0y=0,p0z=0,p0w=0, p1x=0,p1y=0,p1z=0,p1w=0;
        #pragma unroll
        for (int u = 0; u < 8; ++u) {
            int jr = lane + u*64;
            float4 r = row[jr];
            float a0 = att[0][jr], a1 = att[1][jr];
            p0x += a0*r.x; p0y += a0*r.y; p0z += a0*r.z; p0w += a0*r.w;
            p1x += a1*r.x; p1y += a1*r.y; p1z += a1*r.z; p1w += a1*r.w;
        }
        #pragma unroll
        for (int d = 32; d > 0; d >>= 1) {
            p0x += __shfl_down(p0x, d); p0y += __shfl_down(p0y, d);
            p0z += __shfl_down(p0z, d); p0w += __shfl_down(p0w, d);
            p1x += __shfl_down(p1x, d); p1y += __shfl_down(p1y, d);
            p1z += __shfl_down(p1z, d); p1w += __shfl_down(p1w, d);
        }
        if (lane == 0) {
            if (g < 4) {
                *reinterpret_cast<float4*>(&cat[(size_t)(i0+0)*CATF + h*16 + g*4]) =
                    make_float4(p0x, p0y, p0z, p0w);
                *reinterpret_cast<float4*>(&cat[(size_t)(i0+1)*CATF + h*16 + g*4]) =
                    make_float4(p1x, p1y, p1z, p1w);
            } else {
                int e = (g-4)*4;
                optl[0][e] = p0x; optl[0][e+1] = p0y; optl[0][e+2] = p0z; optl[0][e+3] = p0w;
                optl[1][e] = p1x; optl[1][e+1] = p1y; optl[1][e+2] = p1z; optl[1][e+3] = p1w;
            }
        }
    }
    __syncthreads();

    if (tid < 16) {
        int ii = tid >> 3, p = tid & 7;
        int i = i0 + ii;
        float t0 = T[i*16 + 0*4 + 3], t1 = T[i*16 + 1*4 + 3], t2 = T[i*16 + 2*4 + 3];
        float y0 = optl[ii][p*3+0] - t0, y1 = optl[ii][p*3+1] - t1, y2 = optl[ii][p*3+2] - t2;
        float n2 = 0.f;
        #pragma unroll
        for (int x = 0; x < 3; ++x) {
            float w = T[i*16 + 0*4 + x]*y0 + T[i*16 + 1*4 + x]*y1 + T[i*16 + 2*4 + x]*y2;
            cat[(size_t)i*CATF + 192 + x*96 + h*8 + p] = w;
            n2 += w*w;
        }
        cat[(size_t)i*CATF + 480 + h*8 + p] = sqrtf(n2);
    }
}

// ---------------- Kernel 4: pairwise = att @ z -> cat[576:2112] ----------------
// att read from bf16 buffer; z read directly from global (L2/L3-resident).
__global__ __launch_bounds__(512) void k_pair(
    const float* __restrict__ z, const __hip_bfloat16* __restrict__ att16,
    float* __restrict__ cat)
{
    int i = blockIdx.x, tid = threadIdx.x;
    int us = tid >> 7, ht = (tid >> 5) & 3, c4 = tid & 31;
    __shared__ float al[12*NRES];     // att (fp32 in LDS), then partial buffer

    for (int idx = tid; idx < 12*NRES; idx += 512) {
        int h = idx >> 9, j = idx & 511;
        al[idx] = __bfloat162float(att16[((size_t)h*NRES + i)*NRES + j]);
    }
    __syncthreads();

    const float4* z4 = reinterpret_cast<const float4*>(z + (size_t)i*NRES*CZ);
    float4 a0 = {0,0,0,0}, a1 = {0,0,0,0}, a2 = {0,0,0,0};
    int ub = us*128;
    #pragma unroll 4
    for (int u = 0; u < 128; ++u) {
        int jr = ub + u;
        float4 zv = z4[(size_t)jr*32 + c4];
        float w0 = al[(ht    )*NRES + jr];
        float w1 = al[(ht + 4)*NRES + jr];
        float w2 = al[(ht + 8)*NRES + jr];
        a0.x = fmaf(w0, zv.x, a0.x); a0.y = fmaf(w0, zv.y, a0.y);
        a0.z = fmaf(w0, zv.z, a0.z); a0.w = fmaf(w0, zv.w, a0.w);
        a1.x = fmaf(w1, zv.x, a1.x); a1.y = fmaf(w1, zv.y, a1.y);
        a1.z = fmaf(w1, zv.z, a1.z); a1.w = fmaf(w1, zv.w, a1.w);
        a2.x = fmaf(w2, zv.x, a2.x); a2.y = fmaf(w2, zv.y, a2.y);
        a2.z = fmaf(w2, zv.z, a2.z); a2.w = fmaf(w2, zv.w, a2.w);
    }
    __syncthreads();   // al reads done; reuse as partial buffer
    float* pr = al;    // [512 threads][12]
    {
        float* p = &pr[tid*12];
        p[0]=a0.x; p[1]=a0.y; p[2]=a0.z;  p[3]=a0.w;
        p[4]=a1.x; p[5]=a1.y; p[6]=a1.z;  p[7]=a1.w;
        p[8]=a2.x; p[9]=a2.y; p[10]=a2.z; p[11]=a2.w;
    }
    __syncthreads();

    for (int idx = tid; idx < 1536; idx += 512) {
        int h = idx >> 7, c = idx & 127;
        int hh = h & 3, m = h >> 2, cc4 = c >> 2, x = c & 3;
        float v = 0.f;
        #pragma unroll
        for (int uu = 0; uu < 4; ++uu)
            v += pr[(((uu*4 + hh)*32 + cc4))*12 + m*4 + x];
        cat[(size_t)i*CATF + 576 + h*128 + c] = v;
    }
}

// ---------------- Kernel 5a: split-K Wo GEMM (LDS version) ----------------
__global__ __launch_bounds__(384) void k_wo(
    const float* __restrict__ cat, const float* __restrict__ Wo,
    float* __restrict__ part)
{
    int i0 = blockIdx.x * 8;
    int fs = blockIdx.y;
    int f0 = fs * FCHUNK;
    int tid = threadIdx.x;
    __shared__ float cl[8][FCHUNK];
    for (int idx = tid; idx < 8*(FCHUNK/4); idx += 384) {
        int j = idx / (FCHUNK/4), q = idx % (FCHUNK/4);
        *reinterpret_cast<float4*>(&cl[j][q*4]) =
            *reinterpret_cast<const float4*>(&cat[(size_t)(i0+j)*CATF + f0 + q*4]);
    }
    __syncthreads();
    float acc[8] = {0,0,0,0,0,0,0,0};
    const float* wp = Wo + (size_t)f0*CS + tid;
    #pragma unroll 4
    for (int f = 0; f < FCHUNK; ++f) {
        float w = wp[(size_t)f*CS];
        #pragma unroll
        for (int j = 0; j < 8; ++j) acc[j] = fmaf(w, cl[j][f], acc[j]);
    }
    #pragma unroll
    for (int j = 0; j < 8; ++j)
        part[((size_t)fs*NRES + i0 + j)*CS + tid] = acc[j];
}

// ---------------- Kernel 5b: reduce partials + bias ----------------
__global__ __launch_bounds__(384) void k_red(
    const float* __restrict__ part, const float* __restrict__ bo,
    float* __restrict__ out)
{
    int i = blockIdx.x, o = threadIdx.x;
    float a = bo[o];
    #pragma unroll
    for (int s = 0; s < FSPLIT; ++s)
        a += part[((size_t)s*NRES + i)*CS + o];
    out[(size_t)i*CS + o] = a;
}

// ---------------- launch ----------------
extern "C" void kernel_launch(void* const* d_in, const int* in_sizes, int n_in,
                              void* d_out, int out_size, void* d_ws, size_t ws_size,
                              hipStream_t stream)
{
    const float* s   = (const float*)d_in[0];
    const float* z   = (const float*)d_in[1];
    const float* T   = (const float*)d_in[2];
    const float* Wq  = (const float*)d_in[3];  const float* bq  = (const float*)d_in[4];
    const float* Wk  = (const float*)d_in[5];  const float* bk  = (const float*)d_in[6];
    const float* Wv  = (const float*)d_in[7];  const float* bv  = (const float*)d_in[8];
    const float* Wqp = (const float*)d_in[9];  const float* bqp = (const float*)d_in[10];
    const float* Wkp = (const float*)d_in[11]; const float* bkp = (const float*)d_in[12];
    const float* Wvp = (const float*)d_in[13]; const float* bvp = (const float*)d_in[14];
    const float* Wb  = (const float*)d_in[15]; const float* bb  = (const float*)d_in[16];
    const float* Wo  = (const float*)d_in[17]; const float* bo  = (const float*)d_in[18];
    const float* hw  = (const float*)d_in[19];
    float* out = (float*)d_out;
    float* ws  = (float*)d_ws;

    size_t off = 0;
    float* q_s  = ws + off; off += (size_t)NH*NRES*CC;
    float* k_t  = ws + off; off += (size_t)NH*NRES*CC;
    float* v_t  = ws + off; off += (size_t)NH*NRES*CC;
    float* wq   = ws + off; off += (size_t)NH*NRES*12;
    float* wk_t = ws + off; off += (size_t)NH*NRES*12;
    float* wv_t = ws + off; off += (size_t)NH*NRES*24;
    float* qn   = ws + off; off += (size_t)NH*NRES;
    float* kn   = ws + off; off += (size_t)NH*NRES;
    float* bias = ws + off; off += (size_t)NH*NRES*NRES;
    float* cat  = ws + off; off += (size_t)NRES*CATF;
    float* part = ws + off; off += (size_t)FSPLIT*NRES*CS;
    float* praw = ws + off; off += (size_t)NRES*FTOT;
    __hip_bfloat16* att16 = (__hip_bfloat16*)(ws + off);   // 3.1M bf16 = 6.3MB

    k_gemm<<<dim3(NRES/4, 3), dim3(384), 0, stream>>>(
        s, Wq, bq, Wk, bk, Wv, bv, Wqp, bqp, Wkp, bkp, Wvp, bvp, praw);

    k_post<<<dim3(NRES), dim3(256), 0, stream>>>(
        praw, T, q_s, (float4*)k_t, (float4*)v_t, wq, (float4*)wk_t, (float4*)wv_t, qn, kn);

    k_bias<<<dim3(8, NRES), dim3(256), 0, stream>>>(z, Wb, bb, bias);

    k_att<<<dim3(NRES/2, NH), dim3(256), 0, stream>>>(
        q_s, (const float4*)k_t, wq, (const float4*)wk_t, qn, kn, hw, T, bias,
        att16, (const float4*)v_t, (const float4*)wv_t, cat);

    k_pair<<<dim3(NRES), dim3(512), 0, stream>>>(z, att16, cat);

    k_wo<<<dim3(NRES/8, FSPLIT), dim3(384), 0, stream>>>(cat, Wo, part);

    k_red<<<dim3(NRES), dim3(384), 0, stream>>>(part, bo, out);
}

// Round 18
// 155.168 us; speedup vs baseline: 1.3972x; 1.0038x over previous
//
#include <hip/hip_runtime.h>
#include <hip/hip_bf16.h>
#include <math.h>

// Problem constants
#define NRES 512
#define CS 384
#define CZ 128
#define NH 12
#define CC 16
#define NQP 4
#define NPV 8
#define HC (NH*CC)        // 192
#define FTOT 1152         // 192*3 + 144*2 + 288
#define CATF 2112         // 192 + 288 + 96 + 1536
#define FSPLIT 8
#define FCHUNK 264        // 2112/8
#define W_C 0.23570226039551584f   // sqrt(2/(9*4))
#define W_L 0.5773502691896258f    // sqrt(1/3)

// ---------------- Kernel 1a: all projections as one GEMM ----------------
__global__ __launch_bounds__(384) void k_gemm(
    const float* __restrict__ s,
    const float* __restrict__ Wq, const float* __restrict__ bq,
    const float* __restrict__ Wk, const float* __restrict__ bk,
    const float* __restrict__ Wv, const float* __restrict__ bv,
    const float* __restrict__ Wqp, const float* __restrict__ bqp,
    const float* __restrict__ Wkp, const float* __restrict__ bkp,
    const float* __restrict__ Wvp, const float* __restrict__ bvp,
    float* __restrict__ p_raw)
{
    int r0 = blockIdx.x * 4;
    int f  = blockIdx.y * 384 + threadIdx.x;
    const float* W; const float* bia; int col; int stride;
    if      (f < 192) { W = Wq;  bia = bq;  col = f;       stride = 192; }
    else if (f < 384) { W = Wk;  bia = bk;  col = f - 192; stride = 192; }
    else if (f < 576) { W = Wv;  bia = bv;  col = f - 384; stride = 192; }
    else if (f < 720) { W = Wqp; bia = bqp; col = f - 576; stride = 144; }
    else if (f < 864) { W = Wkp; bia = bkp; col = f - 720; stride = 144; }
    else              { W = Wvp; bia = bvp; col = f - 864; stride = 288; }

    float acc[4];
    float b0 = bia[col];
    #pragma unroll
    for (int j = 0; j < 4; ++j) acc[j] = b0;

    const float* srow = s + (size_t)r0 * CS;
    #pragma unroll 4
    for (int i = 0; i < CS; ++i) {
        float w = W[(size_t)i * stride + col];
        #pragma unroll
        for (int j = 0; j < 4; ++j) acc[j] = fmaf(w, srow[j*CS + i], acc[j]);
    }
    #pragma unroll
    for (int j = 0; j < 4; ++j) p_raw[(size_t)(r0 + j)*FTOT + f] = acc[j];
}

// ---------------- Kernel 1b: warp + transpose layouts ----------------
__global__ __launch_bounds__(256) void k_post(
    const float* __restrict__ p_raw, const float* __restrict__ T,
    float* __restrict__ q_s, float4* __restrict__ k_t4, float4* __restrict__ v_t4,
    float* __restrict__ wq, float4* __restrict__ wk_t4, float4* __restrict__ wv_t4,
    float* __restrict__ qn, float* __restrict__ kn)
{
    int n = blockIdx.x;
    int tid = threadIdx.x;
    __shared__ float pl[FTOT];
    __shared__ float Rl[9], tl[3];
    __shared__ float wq_l[144], wk_l[144], wv_l[288];
    __shared__ float sq_part[48], sk_part[48];

    for (int idx = tid; idx < FTOT/4; idx += 256)
        *reinterpret_cast<float4*>(&pl[idx*4]) =
            *reinterpret_cast<const float4*>(&p_raw[(size_t)n*FTOT + idx*4]);
    if (tid < 9)  Rl[tid] = T[n*16 + (tid/3)*4 + (tid%3)];
    if (tid >= 16 && tid < 19) tl[tid-16] = T[n*16 + (tid-16)*4 + 3];
    __syncthreads();

    if (tid < 48) {
        int h = tid >> 2, p = tid & 3;
        float qy0 = pl[576 + 0*48 + h*4 + p], qy1 = pl[576 + 1*48 + h*4 + p], qy2 = pl[576 + 2*48 + h*4 + p];
        float ky0 = pl[720 + 0*48 + h*4 + p], ky1 = pl[720 + 1*48 + h*4 + p], ky2 = pl[720 + 2*48 + h*4 + p];
        float qs2 = 0.f, ks2 = 0.f;
        #pragma unroll
        for (int x = 0; x < 3; ++x) {
            float wqv = Rl[x*3+0]*qy0 + Rl[x*3+1]*qy1 + Rl[x*3+2]*qy2 + tl[x];
            float wkv = Rl[x*3+0]*ky0 + Rl[x*3+1]*ky1 + Rl[x*3+2]*ky2 + tl[x];
            wq_l[h*12 + p*3 + x] = wqv;
            wk_l[h*12 + p*3 + x] = wkv;
            qs2 += wqv*wqv; ks2 += wkv*wkv;
        }
        sq_part[tid] = qs2; sk_part[tid] = ks2;
    } else if (tid >= 64 && tid < 160) {
        int u = tid - 64; int h = u >> 3, p = u & 7;
        float y0 = pl[864 + 0*96 + h*8 + p], y1 = pl[864 + 1*96 + h*8 + p], y2 = pl[864 + 2*96 + h*8 + p];
        #pragma unroll
        for (int x = 0; x < 3; ++x) {
            wv_l[h*24 + p*3 + x] = Rl[x*3+0]*y0 + Rl[x*3+1]*y1 + Rl[x*3+2]*y2 + tl[x];
        }
    }
    __syncthreads();

    if (tid < 48) {
        int h = tid >> 2, c4 = tid & 3;
        float4 qv = *reinterpret_cast<const float4*>(&pl[h*16 + c4*4]);
        qv.x *= 0.25f; qv.y *= 0.25f; qv.z *= 0.25f; qv.w *= 0.25f;
        float4 kv = *reinterpret_cast<const float4*>(&pl[192 + h*16 + c4*4]);
        float4 vv = *reinterpret_cast<const float4*>(&pl[384 + h*16 + c4*4]);
        *reinterpret_cast<float4*>(&q_s[((size_t)h*NRES + n)*16 + c4*4]) = qv;
        k_t4[((size_t)h*4 + c4)*NRES + n] = kv;
        v_t4[((size_t)h*4 + c4)*NRES + n] = vv;
    } else if (tid >= 64 && tid < 100) {
        int u = tid - 64; int h = u / 3, e4 = u % 3;
        float4 kv = *reinterpret_cast<const float4*>(&wk_l[h*12 + e4*4]);
        wk_t4[((size_t)h*3 + e4)*NRES + n] = kv;
    } else if (tid >= 104 && tid < 140) {
        int u = tid - 104; int h = u / 3, e4 = u % 3;
        float4 qv = *reinterpret_cast<const float4*>(&wq_l[h*12 + e4*4]);
        *reinterpret_cast<float4*>(&wq[((size_t)h*NRES + n)*12 + e4*4]) = qv;
    } else if (tid >= 160 && tid < 232) {
        int u = tid - 160; int h = u / 6, e4 = u % 6;
        float4 vv = *reinterpret_cast<const float4*>(&wv_l[h*24 + e4*4]);
        wv_t4[((size_t)h*6 + e4)*NRES + n] = vv;
    } else if (tid >= 232 && tid < 244) {
        int h = tid - 232;
        qn[(size_t)h*NRES + n] = sq_part[h*4] + sq_part[h*4+1] + sq_part[h*4+2] + sq_part[h*4+3];
        kn[(size_t)h*NRES + n] = sk_part[h*4] + sk_part[h*4+1] + sk_part[h*4+2] + sk_part[h*4+3];
    }
}

// ---------------- Kernel 2: bias = z @ Wb + bb -> bf16 [H][N][N] ----------------
// bias magnitude ~0.23, additive in logit -> bf16 abs err ~1e-3 is safe.
__global__ __launch_bounds__(256) void k_bias(
    const float* __restrict__ z, const float* __restrict__ Wb,
    const float* __restrict__ bb, __hip_bfloat16* __restrict__ bias16)
{
    int j0 = blockIdx.x * 64, i = blockIdx.y;
    int tid = threadIdx.x;
    int r = tid & 63, p = tid >> 6;   // p = wave index (0..3)
    __shared__ float zl[64*132];
    __shared__ float partial[4][12][64];
    __shared__ float bbl[12];

    if (tid < 12) bbl[tid] = bb[tid];
    const float4* zsrc = reinterpret_cast<const float4*>(z + ((size_t)i*NRES + j0)*CZ);
    #pragma unroll
    for (int it = 0; it < 8; ++it) {
        int idx = it*256 + tid;
        int j = idx >> 5, c4 = idx & 31;
        *reinterpret_cast<float4*>(&zl[j*132 + c4*4]) = zsrc[idx];
    }
    __syncthreads();

    float acc[12] = {0,0,0,0,0,0,0,0,0,0,0,0};
    for (int it = 0; it < 8; ++it) {
        int c4 = __builtin_amdgcn_readfirstlane(p*8 + it);   // wave-uniform
        const float* wb = Wb + c4*48;
        float4 zv = *reinterpret_cast<const float4*>(&zl[r*132 + c4*4]);
        #pragma unroll
        for (int h = 0; h < 12; ++h) {
            acc[h] = fmaf(zv.x, wb[h],
                     fmaf(zv.y, wb[12+h],
                     fmaf(zv.z, wb[24+h],
                     fmaf(zv.w, wb[36+h], acc[h]))));
        }
    }
    #pragma unroll
    for (int h = 0; h < 12; ++h) partial[p][h][r] = acc[h];
    __syncthreads();

    #pragma unroll
    for (int u = 0; u < 3; ++u) {
        int idx = u*256 + tid;
        int h = idx >> 6, rr = idx & 63;
        float v = partial[0][h][rr] + partial[1][h][rr]
                + partial[2][h][rr] + partial[3][h][rr] + bbl[h];
        bias16[((size_t)h*NRES + i)*NRES + j0 + rr] = __float2bfloat16(v);
    }
}

// ------- Kernel 3: att softmax for 2 residues/block (fp32 streams, bf16 bias/att) -------
__global__ __launch_bounds__(256) void k_att(
    const float* __restrict__ q_s, const float4* __restrict__ k_t4,
    const float* __restrict__ wq, const float4* __restrict__ wk_t4,
    const float* __restrict__ qn, const float* __restrict__ kn,
    const float* __restrict__ hw, const float* __restrict__ T,
    const __hip_bfloat16* __restrict__ bias16,
    __hip_bfloat16* __restrict__ att16,
    const float4* __restrict__ v_t4, const float4* __restrict__ wv_t4,
    float* __restrict__ cat)
{
    int i0 = blockIdx.x * 2, h = blockIdx.y;
    int tid = threadIdx.x;
    int wave = tid >> 6, lane = tid & 63;
    __shared__ float ql[2][16], wql[2][12];
    __shared__ float att[2][NRES];
    __shared__ float redm[2][4], reds[2][4];
    __shared__ float optl[2][24];
    __shared__ float sQn[2], sG;

    if (tid < 32) {
        int ii = tid >> 4, c = tid & 15;
        ql[ii][c] = q_s[((size_t)h*NRES + i0+ii)*16 + c];
    } else if (tid < 56) {
        int u = tid - 32; int ii = u / 12, e = u % 12;
        wql[ii][e] = wq[((size_t)h*NRES + i0+ii)*12 + e];
    } else if (tid < 58) {
        int ii = tid - 56;
        sQn[ii] = qn[(size_t)h*NRES + i0+ii];
    } else if (tid == 58) {
        float x = hw[h];
        float sp = (x > 20.f) ? x : log1pf(expf(x));
        sG = sp * W_C * 0.5f;
    }
    __syncthreads();
    float gam = sG;

    float lg[2][2];
    #pragma unroll
    for (int m = 0; m < 2; ++m) {
        int j = tid + m*256;
        float4 kv0 = k_t4[((size_t)h*4 + 0)*NRES + j];
        float4 kv1 = k_t4[((size_t)h*4 + 1)*NRES + j];
        float4 kv2 = k_t4[((size_t)h*4 + 2)*NRES + j];
        float4 kv3 = k_t4[((size_t)h*4 + 3)*NRES + j];
        float4 wv0 = wk_t4[((size_t)h*3 + 0)*NRES + j];
        float4 wv1 = wk_t4[((size_t)h*3 + 1)*NRES + j];
        float4 wv2 = wk_t4[((size_t)h*3 + 2)*NRES + j];
        float knj = kn[(size_t)h*NRES + j];
        #pragma unroll
        for (int ii = 0; ii < 2; ++ii) {
            float qk = ql[ii][0]*kv0.x + ql[ii][1]*kv0.y + ql[ii][2]*kv0.z + ql[ii][3]*kv0.w
                     + ql[ii][4]*kv1.x + ql[ii][5]*kv1.y + ql[ii][6]*kv1.z + ql[ii][7]*kv1.w
                     + ql[ii][8]*kv2.x + ql[ii][9]*kv2.y + ql[ii][10]*kv2.z + ql[ii][11]*kv2.w
                     + ql[ii][12]*kv3.x + ql[ii][13]*kv3.y + ql[ii][14]*kv3.z + ql[ii][15]*kv3.w;
            float dd = wql[ii][0]*wv0.x + wql[ii][1]*wv0.y + wql[ii][2]*wv0.z + wql[ii][3]*wv0.w
                     + wql[ii][4]*wv1.x + wql[ii][5]*wv1.y + wql[ii][6]*wv1.z + wql[ii][7]*wv1.w
                     + wql[ii][8]*wv2.x + wql[ii][9]*wv2.y + wql[ii][10]*wv2.z + wql[ii][11]*wv2.w;
            float d2 = sQn[ii] + knj - 2.f*dd;
            float bv = __bfloat162float(bias16[((size_t)h*NRES + i0+ii)*NRES + j]);
            lg[ii][m] = W_L * (qk + bv - gam*d2);
        }
    }

    #pragma unroll
    for (int ii = 0; ii < 2; ++ii) {
        float mx = fmaxf(lg[ii][0], lg[ii][1]);
        #pragma unroll
        for (int d = 32; d > 0; d >>= 1) mx = fmaxf(mx, __shfl_xor(mx, d));
        if (lane == 0) redm[ii][wave] = mx;
    }
    __syncthreads();
    #pragma unroll
    for (int ii = 0; ii < 2; ++ii) {
        float mx = fmaxf(fmaxf(redm[ii][0], redm[ii][1]), fmaxf(redm[ii][2], redm[ii][3]));
        float e0 = __expf(lg[ii][0]-mx), e1 = __expf(lg[ii][1]-mx);
        lg[ii][0] = e0; lg[ii][1] = e1;
        float sm = e0 + e1;
        #pragma unroll
        for (int d = 32; d > 0; d >>= 1) sm += __shfl_xor(sm, d);
        if (lane == 0) reds[ii][wave] = sm;
    }
    __syncthreads();
    #pragma unroll
    for (int ii = 0; ii < 2; ++ii) {
        float inv = 1.f / (reds[ii][0]+reds[ii][1]+reds[ii][2]+reds[ii][3]);
        float a0 = lg[ii][0]*inv, a1 = lg[ii][1]*inv;
        att[ii][tid] = a0; att[ii][tid+256] = a1;
        att16[((size_t)h*NRES + i0+ii)*NRES + tid]       = __float2bfloat16(a0);
        att16[((size_t)h*NRES + i0+ii)*NRES + tid + 256] = __float2bfloat16(a1);
    }
    __syncthreads();

    for (int g = wave; g < 10; g += 4) {
        const float4* row = (g < 4) ? &v_t4[((size_t)h*4 + g)*NRES]
                                    : &wv_t4[((size_t)h*6 + (g-4))*NRES];
        float p0x=0,p0y=0,p0z=0,p0w=0, p1x=0,p1y=0,p1z=0,p1w=0;
        #pragma unroll
        for (int u = 0; u < 8; ++u) {
            int jr = lane + u*64;
            float4 r = row[jr];
            float a0 = att[0][jr], a1 = att[1][jr];
            p0x += a0*r.x; p0y += a0*r.y; p0z += a0*r.z; p0w += a0*r.w;
            p1x += a1*r.x; p1y += a1*r.y; p1z += a1*r.z; p1w += a1*r.w;
        }
        #pragma unroll
        for (int d = 32; d > 0; d >>= 1) {
            p0x += __shfl_down(p0x, d); p0y += __shfl_down(p0y, d);
            p0z += __shfl_down(p0z, d); p0w += __shfl_down(p0w, d);
            p1x += __shfl_down(p1x, d); p1y += __shfl_down(p1y, d);
            p1z += __shfl_down(p1z, d); p1w += __shfl_down(p1w, d);
        }
        if (lane == 0) {
            if (g < 4) {
                *reinterpret_cast<float4*>(&cat[(size_t)(i0+0)*CATF + h*16 + g*4]) =
                    make_float4(p0x, p0y, p0z, p0w);
                *reinterpret_cast<float4*>(&cat[(size_t)(i0+1)*CATF + h*16 + g*4]) =
                    make_float4(p1x, p1y, p1z, p1w);
            } else {
                int e = (g-4)*4;
                optl[0][e] = p0x; optl[0][e+1] = p0y; optl[0][e+2] = p0z; optl[0][e+3] = p0w;
                optl[1][e] = p1x; optl[1][e+1] = p1y; optl[1][e+2] = p1z; optl[1][e+3] = p1w;
            }
        }
    }
    __syncthreads();

    if (tid < 16) {
        int ii = tid >> 3, p = tid & 7;
        int i = i0 + ii;
        float t0 = T[i*16 + 0*4 + 3], t1 = T[i*16 + 1*4 + 3], t2 = T[i*16 + 2*4 + 3];
        float y0 = optl[ii][p*3+0] - t0, y1 = optl[ii][p*3+1] - t1, y2 = optl[ii][p*3+2] - t2;
        float n2 = 0.f;
        #pragma unroll
        for (int x = 0; x < 3; ++x) {
            float w = T[i*16 + 0*4 + x]*y0 + T[i*16 + 1*4 + x]*y1 + T[i*16 + 2*4 + x]*y2;
            cat[(size_t)i*CATF + 192 + x*96 + h*8 + p] = w;
            n2 += w*w;
        }
        cat[(size_t)i*CATF + 480 + h*8 + p] = sqrtf(n2);
    }
}

// ---------------- Kernel 4: pairwise = att @ z -> cat[576:2112] ----------------
__global__ __launch_bounds__(512) void k_pair(
    const float* __restrict__ z, const __hip_bfloat16* __restrict__ att16,
    float* __restrict__ cat)
{
    int i = blockIdx.x, tid = threadIdx.x;
    int us = tid >> 7, ht = (tid >> 5) & 3, c4 = tid & 31;
    __shared__ float al[12*NRES];     // att (fp32 in LDS), then partial buffer

    for (int idx = tid; idx < 12*NRES; idx += 512) {
        int h = idx >> 9, j = idx & 511;
        al[idx] = __bfloat162float(att16[((size_t)h*NRES + i)*NRES + j]);
    }
    __syncthreads();

    const float4* z4 = reinterpret_cast<const float4*>(z + (size_t)i*NRES*CZ);
    float4 a0 = {0,0,0,0}, a1 = {0,0,0,0}, a2 = {0,0,0,0};
    int ub = us*128;
    #pragma unroll 4
    for (int u = 0; u < 128; ++u) {
        int jr = ub + u;
        float4 zv = z4[(size_t)jr*32 + c4];
        float w0 = al[(ht    )*NRES + jr];
        float w1 = al[(ht + 4)*NRES + jr];
        float w2 = al[(ht + 8)*NRES + jr];
        a0.x = fmaf(w0, zv.x, a0.x); a0.y = fmaf(w0, zv.y, a0.y);
        a0.z = fmaf(w0, zv.z, a0.z); a0.w = fmaf(w0, zv.w, a0.w);
        a1.x = fmaf(w1, zv.x, a1.x); a1.y = fmaf(w1, zv.y, a1.y);
        a1.z = fmaf(w1, zv.z, a1.z); a1.w = fmaf(w1, zv.w, a1.w);
        a2.x = fmaf(w2, zv.x, a2.x); a2.y = fmaf(w2, zv.y, a2.y);
        a2.z = fmaf(w2, zv.z, a2.z); a2.w = fmaf(w2, zv.w, a2.w);
    }
    __syncthreads();   // al reads done; reuse as partial buffer
    float* pr = al;    // [512 threads][12]
    {
        float* p = &pr[tid*12];
        p[0]=a0.x; p[1]=a0.y; p[2]=a0.z;  p[3]=a0.w;
        p[4]=a1.x; p[5]=a1.y; p[6]=a1.z;  p[7]=a1.w;
        p[8]=a2.x; p[9]=a2.y; p[10]=a2.z; p[11]=a2.w;
    }
    __syncthreads();

    for (int idx = tid; idx < 1536; idx += 512) {
        int h = idx >> 7, c = idx & 127;
        int hh = h & 3, m = h >> 2, cc4 = c >> 2, x = c & 3;
        float v = 0.f;
        #pragma unroll
        for (int uu = 0; uu < 4; ++uu)
            v += pr[(((uu*4 + hh)*32 + cc4))*12 + m*4 + x];
        cat[(size_t)i*CATF + 576 + h*128 + c] = v;
    }
}

// ---------------- Kernel 5a: split-K Wo GEMM (LDS version) ----------------
__global__ __launch_bounds__(384) void k_wo(
    const float* __restrict__ cat, const float* __restrict__ Wo,
    float* __restrict__ part)
{
    int i0 = blockIdx.x * 8;
    int fs = blockIdx.y;
    int f0 = fs * FCHUNK;
    int tid = threadIdx.x;
    __shared__ float cl[8][FCHUNK];
    for (int idx = tid; idx < 8*(FCHUNK/4); idx += 384) {
        int j = idx / (FCHUNK/4), q = idx % (FCHUNK/4);
        *reinterpret_cast<float4*>(&cl[j][q*4]) =
            *reinterpret_cast<const float4*>(&cat[(size_t)(i0+j)*CATF + f0 + q*4]);
    }
    __syncthreads();
    float acc[8] = {0,0,0,0,0,0,0,0};
    const float* wp = Wo + (size_t)f0*CS + tid;
    #pragma unroll 4
    for (int f = 0; f < FCHUNK; ++f) {
        float w = wp[(size_t)f*CS];
        #pragma unroll
        for (int j = 0; j < 8; ++j) acc[j] = fmaf(w, cl[j][f], acc[j]);
    }
    #pragma unroll
    for (int j = 0; j < 8; ++j)
        part[((size_t)fs*NRES + i0 + j)*CS + tid] = acc[j];
}

// ---------------- Kernel 5b: reduce partials + bias ----------------
__global__ __launch_bounds__(384) void k_red(
    const float* __restrict__ part, const float* __restrict__ bo,
    float* __restrict__ out)
{
    int i = blockIdx.x, o = threadIdx.x;
    float a = bo[o];
    #pragma unroll
    for (int s = 0; s < FSPLIT; ++s)
        a += part[((size_t)s*NRES + i)*CS + o];
    out[(size_t)i*CS + o] = a;
}

// ---------------- launch ----------------
extern "C" void kernel_launch(void* const* d_in, const int* in_sizes, int n_in,
                              void* d_out, int out_size, void* d_ws, size_t ws_size,
                              hipStream_t stream)
{
    const float* s   = (const float*)d_in[0];
    const float* z   = (const float*)d_in[1];
    const float* T   = (const float*)d_in[2];
    const float* Wq  = (const float*)d_in[3];  const float* bq  = (const float*)d_in[4];
    const float* Wk  = (const float*)d_in[5];  const float* bk  = (const float*)d_in[6];
    const float* Wv  = (const float*)d_in[7];  const float* bv  = (const float*)d_in[8];
    const float* Wqp = (const float*)d_in[9];  const float* bqp = (const float*)d_in[10];
    const float* Wkp = (const float*)d_in[11]; const float* bkp = (const float*)d_in[12];
    const float* Wvp = (const float*)d_in[13]; const float* bvp = (const float*)d_in[14];
    const float* Wb  = (const float*)d_in[15]; const float* bb  = (const float*)d_in[16];
    const float* Wo  = (const float*)d_in[17]; const float* bo  = (const float*)d_in[18];
    const float* hw  = (const float*)d_in[19];
    float* out = (float*)d_out;
    float* ws  = (float*)d_ws;

    size_t off = 0;
    float* q_s  = ws + off; off += (size_t)NH*NRES*CC;
    float* k_t  = ws + off; off += (size_t)NH*NRES*CC;
    float* v_t  = ws + off; off += (size_t)NH*NRES*CC;
    float* wq   = ws + off; off += (size_t)NH*NRES*12;
    float* wk_t = ws + off; off += (size_t)NH*NRES*12;
    float* wv_t = ws + off; off += (size_t)NH*NRES*24;
    float* qn   = ws + off; off += (size_t)NH*NRES;
    float* kn   = ws + off; off += (size_t)NH*NRES;
    float* cat  = ws + off; off += (size_t)NRES*CATF;
    float* part = ws + off; off += (size_t)FSPLIT*NRES*CS;
    float* praw = ws + off; off += (size_t)NRES*FTOT;
    __hip_bfloat16* bias16 = (__hip_bfloat16*)(ws + off); off += (size_t)NH*NRES*NRES/2;
    __hip_bfloat16* att16  = (__hip_bfloat16*)(ws + off);

    k_gemm<<<dim3(NRES/4, 3), dim3(384), 0, stream>>>(
        s, Wq, bq, Wk, bk, Wv, bv, Wqp, bqp, Wkp, bkp, Wvp, bvp, praw);

    k_post<<<dim3(NRES), dim3(256), 0, stream>>>(
        praw, T, q_s, (float4*)k_t, (float4*)v_t, wq, (float4*)wk_t, (float4*)wv_t, qn, kn);

    k_bias<<<dim3(8, NRES), dim3(256), 0, stream>>>(z, Wb, bb, bias16);

    k_att<<<dim3(NRES/2, NH), dim3(256), 0, stream>>>(
        q_s, (const float4*)k_t, wq, (const float4*)wk_t, qn, kn, hw, T, bias16,
        att16, (const float4*)v_t, (const float4*)wv_t, cat);

    k_pair<<<dim3(NRES), dim3(512), 0, stream>>>(z, att16, cat);

    k_wo<<<dim3(NRES/8, FSPLIT), dim3(384), 0, stream>>>(cat, Wo, part);

    k_red<<<dim3(NRES), dim3(384), 0, stream>>>(part, bo, out);
}